// Round 2
// baseline (922.793 us; speedup 1.0000x reference)
//
#include <hip/hip_runtime.h>
#include <hip/hip_bf16.h>

typedef __hip_bfloat16 bf16;
typedef __attribute__((ext_vector_type(8))) short short8;
typedef __attribute__((ext_vector_type(4))) float floatx4;

#define L_SEQ 4096
#define B_SZ 4
#define NROW 16384          // B*L
#define NK 12
#define HD 64
#define DIM_CONV 1548
#define DIM_CONV_PAD 1664
#define OUT_CPLX 1536
#define CS_LD 1552          // padded row stride (bf16 elems) -> 3104B, 16B aligned
#define KSIZE 4

__device__ __forceinline__ float bf2f(bf16 v) { return __bfloat162float(v); }
__device__ __forceinline__ float sigmoidf_(float x) { return 1.0f / (1.0f + expf(-x)); }
__device__ __forceinline__ float siluf_(float x) { return x * sigmoidf_(x); }
__device__ __forceinline__ float softplusf_(float x) {
    return fmaxf(x, 0.0f) + log1pf(expf(-fabsf(x)));
}

// ---------------------------------------------------------------------------
// bf16 MFMA GEMM: C[M x N] = A[M x Kd] * Bt[N x Kd]^T. 128x128 tile, BK=32.
// LDS chunk q = k8*128 + row holds X[row][k8*8..+8].
//   A frag: A[m=lane&15][k=(lane>>4)*8+j]; B frag: B[k][n=lane&15]
//   C/D:    col=lane&15, row=(lane>>4)*4+reg
// ---------------------------------------------------------------------------
#define GEMM_CORE(A_, lda_, Bt_, ldb_, Kd_)                                              \
    __shared__ __align__(16) short lds_a[4][128][8];                                     \
    __shared__ __align__(16) short lds_b[4][128][8];                                     \
    const int tid = threadIdx.x;                                                         \
    const int wave = tid >> 6;                                                           \
    const int lane = tid & 63;                                                           \
    const int q0 = wave * 64 + lane;                                                     \
    const int q1 = q0 + 256;                                                             \
    const bf16* ga0 = A_ + (size_t)(q0 & 127) * lda_ + ((q0 >> 7) << 3);                 \
    const bf16* ga1 = A_ + (size_t)(q1 & 127) * lda_ + ((q1 >> 7) << 3);                 \
    const bf16* gb0 = Bt_ + (size_t)(q0 & 127) * ldb_ + ((q0 >> 7) << 3);                \
    const bf16* gb1 = Bt_ + (size_t)(q1 & 127) * ldb_ + ((q1 >> 7) << 3);                \
    short* la0 = &lds_a[0][0][0] + wave * 512;                                           \
    short* la1 = &lds_a[0][0][0] + 2048 + wave * 512;                                    \
    short* lb0 = &lds_b[0][0][0] + wave * 512;                                           \
    short* lb1 = &lds_b[0][0][0] + 2048 + wave * 512;                                    \
    floatx4 acc[4][4];                                                                   \
    _Pragma("unroll") for (int i = 0; i < 4; i++)                                        \
        _Pragma("unroll") for (int j = 0; j < 4; j++)                                    \
            acc[i][j] = (floatx4){0.f, 0.f, 0.f, 0.f};                                   \
    const int wm = (wave >> 1) * 64;                                                     \
    const int wn = (wave & 1) * 64;                                                      \
    const int lrow = lane & 15;                                                          \
    const int lk8 = lane >> 4;                                                           \
    for (int k0 = 0; k0 < Kd_; k0 += 32) {                                               \
        __builtin_amdgcn_global_load_lds((const __attribute__((address_space(1))) void*)ga0, \
                                         (__attribute__((address_space(3))) void*)la0, 16, 0, 0); \
        __builtin_amdgcn_global_load_lds((const __attribute__((address_space(1))) void*)ga1, \
                                         (__attribute__((address_space(3))) void*)la1, 16, 0, 0); \
        __builtin_amdgcn_global_load_lds((const __attribute__((address_space(1))) void*)gb0, \
                                         (__attribute__((address_space(3))) void*)lb0, 16, 0, 0); \
        __builtin_amdgcn_global_load_lds((const __attribute__((address_space(1))) void*)gb1, \
                                         (__attribute__((address_space(3))) void*)lb1, 16, 0, 0); \
        ga0 += 32; ga1 += 32; gb0 += 32; gb1 += 32;                                      \
        __syncthreads();                                                                 \
        short8 af[4], bfv[4];                                                            \
        _Pragma("unroll") for (int i = 0; i < 4; i++)                                    \
            af[i] = *(const short8*)(&lds_a[lk8][wm + i * 16 + lrow][0]);                \
        _Pragma("unroll") for (int j = 0; j < 4; j++)                                    \
            bfv[j] = *(const short8*)(&lds_b[lk8][wn + j * 16 + lrow][0]);               \
        _Pragma("unroll") for (int i = 0; i < 4; i++)                                    \
            _Pragma("unroll") for (int j = 0; j < 4; j++)                                \
                acc[i][j] = __builtin_amdgcn_mfma_f32_16x16x32_bf16(af[i], bfv[j], acc[i][j], 0, 0, 0); \
        __syncthreads();                                                                 \
    }

template <bool OUT_BF16>
__global__ __launch_bounds__(256, 2) void gemm_kernel(
    const bf16* __restrict__ A, int lda,
    const bf16* __restrict__ Bt, int ldb,
    void* __restrict__ Cv, int ldc, int Kd)
{
    const bf16* Ab = A + (size_t)blockIdx.x * 128 * lda;
    const bf16* Bb = Bt + (size_t)blockIdx.y * 128 * ldb;
    GEMM_CORE(Ab, lda, Bb, ldb, Kd)
    const int orow = blockIdx.x * 128 + wm + (lk8 << 2);
    const int ocol = blockIdx.y * 128 + wn + lrow;
    if (OUT_BF16) {
        bf16* C = (bf16*)Cv;
#pragma unroll
        for (int i = 0; i < 4; i++)
#pragma unroll
            for (int j = 0; j < 4; j++)
#pragma unroll
                for (int r = 0; r < 4; r++)
                    C[(size_t)(orow + i * 16 + r) * ldc + (ocol + j * 16)] =
                        __float2bfloat16(acc[i][j][r]);
    } else {
        float* C = (float*)Cv;
#pragma unroll
        for (int i = 0; i < 4; i++)
#pragma unroll
            for (int j = 0; j < 4; j++)
#pragma unroll
                for (int r = 0; r < 4; r++)
                    C[(size_t)(orow + i * 16 + r) * ldc + (ocol + j * 16)] = acc[i][j][r];
    }
}

// Readout GEMM with fused GLU epilogue. Bt columns are pair-interleaved:
// paired col 2j = val_j, 2j+1 = gate_j. Even lane gets gate via shfl_xor(1).
// Output y[row, z*192 + j], ldc 2304, bf16.
__global__ __launch_bounds__(256, 2) void gemm_readout_glu(
    const bf16* __restrict__ A, int lda, long a_zoff,
    const bf16* __restrict__ Bt, int ldb, long b_zoff,
    bf16* __restrict__ Y, int Kd)
{
    const int z = blockIdx.z;
    const bf16* Ab = A + (long)z * a_zoff + (size_t)blockIdx.x * 128 * lda;
    const bf16* Bb = Bt + (long)z * b_zoff + (size_t)blockIdx.y * 128 * ldb;
    GEMM_CORE(Ab, lda, Bb, ldb, Kd)
    const int orow = blockIdx.x * 128 + wm + (lk8 << 2);
    const int pcol0 = blockIdx.y * 128 + wn + lrow;   // paired col
    const bool is_v = ((lane & 1) == 0);
    bf16* Yk = Y + (long)z * 192;
#pragma unroll
    for (int i = 0; i < 4; i++)
#pragma unroll
        for (int j = 0; j < 4; j++)
#pragma unroll
            for (int r = 0; r < 4; r++) {
                float v = acc[i][j][r];
                float g = __shfl_xor(v, 1);
                float o = v * sigmoidf_(g);
                if (is_v)
                    Yk[(size_t)(orow + i * 16 + r) * 2304 + ((pcol0 + j * 16) >> 1)] =
                        __float2bfloat16(o);
            }
}

// ---------------------------------------------------------------------------
// fp32 -> bf16 conversions / weight transposes
// ---------------------------------------------------------------------------
__global__ void convert_f2b(const float* __restrict__ in, bf16* __restrict__ out, long n)
{
    long gid = ((long)blockIdx.x * 256 + threadIdx.x) * 4;
    if (gid >= n) return;
    float4 v = *(const float4*)(in + gid);
    out[gid + 0] = __float2bfloat16(v.x);
    out[gid + 1] = __float2bfloat16(v.y);
    out[gid + 2] = __float2bfloat16(v.z);
    out[gid + 3] = __float2bfloat16(v.w);
}

__global__ void transpose_pad_f2b(const float* __restrict__ in, bf16* __restrict__ out,
                                  int R, int C, int Cp)
{
    long gid = (long)blockIdx.x * 256 + threadIdx.x;
    if (gid >= (long)Cp * R) return;
    int r = (int)(gid % R);
    int n = (int)(gid / R);
    out[gid] = __float2bfloat16((n < C) ? in[(size_t)r * C + n] : 0.0f);
}

// W_readout (12,128,384) fp32 -> WT_RO (12,384,128) bf16, pair-interleaved cols
__global__ void transpose_ro_f2b(const float* __restrict__ in, bf16* __restrict__ out)
{
    long gid = (long)blockIdx.x * 256 + threadIdx.x;
    if (gid >= 12L * 384 * 128) return;
    int f = (int)(gid % 128);
    int rest = (int)(gid / 128);
    int n = rest % 384;
    int k = rest / 384;
    int src = (n & 1) ? (192 + (n >> 1)) : (n >> 1);
    out[gid] = __float2bfloat16(in[((size_t)k * 128 + f) * 384 + src]);
}

// ---------------------------------------------------------------------------
// Fused conv+transform+scan. Pass A: per-chunk sums. Pass C: write cumsum (bf16)
// and qbuf. Thread = (b, chunk, cv); rolling 4-tap window over 64 positions.
// Stack channels: [0,12)=p_w(k), [12,780)=re(cv), [780,1548)=im(cv).
// ---------------------------------------------------------------------------
struct KvParams {
    float wp[4], ws4[4];
    float ss, sb, slope, theta, ps;
};

__device__ __forceinline__ void load_kv_params(
    KvParams& P, int cv, int k,
    const float* conv_w, const float* theta_raw, const float* decay,
    const float* sscale, const float* sbias, const float* pscale)
{
#pragma unroll
    for (int t = 0; t < 4; t++) {
        P.wp[t] = conv_w[t * DIM_CONV + cv];
        P.ws4[t] = conv_w[t * DIM_CONV + 768 + k];
    }
    P.ss = sscale[k];
    P.sb = sbias[k];
    P.slope = softplusf_(decay[k]);
    P.theta = 0.001f + 2.999f * sigmoidf_(theta_raw[cv]);
    P.ps = pscale[k];
}

__global__ __launch_bounds__(256) void scan_pass_a_f(
    const bf16* __restrict__ z0, const float* __restrict__ conv_w,
    const float* __restrict__ theta_raw, const float* __restrict__ decay,
    const float* __restrict__ sscale, const float* __restrict__ sbias,
    const float* __restrict__ pscale, float* __restrict__ sums)
{
    int gid = blockIdx.x * 256 + threadIdx.x;
    if (gid >= B_SZ * 64 * 780) return;
    int cv = gid % 780;
    int rest = gid / 780;        // b*64 + chunk
    int chunk = rest & 63;
    int b = rest >> 6;
    int l0 = chunk * 64;
    const bf16* zb = z0 + (size_t)b * L_SEQ * DIM_CONV_PAD;

    if (cv < 768) {
        int k = cv >> 6;
        KvParams P;
        load_kv_params(P, cv, k, conv_w, theta_raw, decay, sscale, sbias, pscale);
        float hp1 = (l0 >= 3) ? bf2f(zb[(size_t)(l0 - 3) * DIM_CONV_PAD + cv]) : 0.f;
        float hp2 = (l0 >= 2) ? bf2f(zb[(size_t)(l0 - 2) * DIM_CONV_PAD + cv]) : 0.f;
        float hp3 = (l0 >= 1) ? bf2f(zb[(size_t)(l0 - 1) * DIM_CONV_PAD + cv]) : 0.f;
        float hs1 = (l0 >= 3) ? bf2f(zb[(size_t)(l0 - 3) * DIM_CONV_PAD + 768 + k]) : 0.f;
        float hs2 = (l0 >= 2) ? bf2f(zb[(size_t)(l0 - 2) * DIM_CONV_PAD + 768 + k]) : 0.f;
        float hs3 = (l0 >= 1) ? bf2f(zb[(size_t)(l0 - 1) * DIM_CONV_PAD + 768 + k]) : 0.f;
        float sum_re = 0.f, sum_im = 0.f;
        for (int i = 0; i < 64; i++) {
            int l = l0 + i;
            float cp = bf2f(zb[(size_t)l * DIM_CONV_PAD + cv]);
            float cs_ = bf2f(zb[(size_t)l * DIM_CONV_PAD + 768 + k]);
            float kv = siluf_(P.wp[0] * hp1 + P.wp[1] * hp2 + P.wp[2] * hp3 + P.wp[3] * cp);
            float s = siluf_(P.ws4[0] * hs1 + P.ws4[1] * hs2 + P.ws4[2] * hs3 + P.ws4[3] * cs_);
            hp1 = hp2; hp2 = hp3; hp3 = cp;
            hs1 = hs2; hs2 = hs3; hs3 = cs_;
            float pw = softplusf_(P.ss * s + P.sb) * expf(-P.slope * (float)(L_SEQ - 1 - l));
            pw = fminf(fmaxf(pw, 1e-4f), 5000.0f);
            float ksv = kv * P.ps;
            float phi = ksv / (1.0f + fabsf(ksv)) * P.theta;
            float sn, cn;
            sincosf(phi, &sn, &cn);
            float kvw = kv * pw;
            sum_re += kvw * cn;
            sum_im += kvw * sn;
        }
        sums[(size_t)rest * DIM_CONV + 12 + cv] = sum_re;
        sums[(size_t)rest * DIM_CONV + 780 + cv] = sum_im;
    } else {
        int k = cv - 768;
        float w0 = conv_w[0 * DIM_CONV + 768 + k], w1 = conv_w[1 * DIM_CONV + 768 + k];
        float w2 = conv_w[2 * DIM_CONV + 768 + k], w3 = conv_w[3 * DIM_CONV + 768 + k];
        float ss = sscale[k], sb = sbias[k];
        float slope = softplusf_(decay[k]);
        float h1 = (l0 >= 3) ? bf2f(zb[(size_t)(l0 - 3) * DIM_CONV_PAD + 768 + k]) : 0.f;
        float h2 = (l0 >= 2) ? bf2f(zb[(size_t)(l0 - 2) * DIM_CONV_PAD + 768 + k]) : 0.f;
        float h3 = (l0 >= 1) ? bf2f(zb[(size_t)(l0 - 1) * DIM_CONV_PAD + 768 + k]) : 0.f;
        float sum_pw = 0.f;
        for (int i = 0; i < 64; i++) {
            int l = l0 + i;
            float c = bf2f(zb[(size_t)l * DIM_CONV_PAD + 768 + k]);
            float s = siluf_(w0 * h1 + w1 * h2 + w2 * h3 + w3 * c);
            h1 = h2; h2 = h3; h3 = c;
            float pw = softplusf_(ss * s + sb) * expf(-slope * (float)(L_SEQ - 1 - l));
            sum_pw += fminf(fmaxf(pw, 1e-4f), 5000.0f);
        }
        sums[(size_t)rest * DIM_CONV + k] = sum_pw;
    }
}

__global__ void scan_mid(float* __restrict__ sums)
{
    int gid = blockIdx.x * 256 + threadIdx.x;
    if (gid >= B_SZ * DIM_CONV) return;
    int c = gid % DIM_CONV;
    int b = gid / DIM_CONV;
    float run = 0.f;
    for (int i = 0; i < 64; i++) {
        size_t idx = ((size_t)(b * 64 + i)) * DIM_CONV + c;
        float v = sums[idx];
        sums[idx] = run;
        run += v;
    }
}

__global__ __launch_bounds__(256) void scan_pass_c_f(
    const bf16* __restrict__ z0, const float* __restrict__ conv_w,
    const float* __restrict__ theta_raw, const float* __restrict__ decay,
    const float* __restrict__ sscale, const float* __restrict__ sbias,
    const float* __restrict__ pscale, const float* __restrict__ sums,
    bf16* __restrict__ cs, bf16* __restrict__ qbuf)
{
    int gid = blockIdx.x * 256 + threadIdx.x;
    if (gid >= B_SZ * 64 * DIM_CONV) return;
    int cv = gid % DIM_CONV;
    int rest = gid / DIM_CONV;
    int chunk = rest & 63;
    int b = rest >> 6;
    int l0 = chunk * 64;
    const bf16* zb = z0 + (size_t)b * L_SEQ * DIM_CONV_PAD;
    bf16* csb = cs + (size_t)b * L_SEQ * CS_LD;

    if (cv < 768) {
        int k = cv >> 6;
        KvParams P;
        load_kv_params(P, cv, k, conv_w, theta_raw, decay, sscale, sbias, pscale);
        float hp1 = (l0 >= 3) ? bf2f(zb[(size_t)(l0 - 3) * DIM_CONV_PAD + cv]) : 0.f;
        float hp2 = (l0 >= 2) ? bf2f(zb[(size_t)(l0 - 2) * DIM_CONV_PAD + cv]) : 0.f;
        float hp3 = (l0 >= 1) ? bf2f(zb[(size_t)(l0 - 1) * DIM_CONV_PAD + cv]) : 0.f;
        float hs1 = (l0 >= 3) ? bf2f(zb[(size_t)(l0 - 3) * DIM_CONV_PAD + 768 + k]) : 0.f;
        float hs2 = (l0 >= 2) ? bf2f(zb[(size_t)(l0 - 2) * DIM_CONV_PAD + 768 + k]) : 0.f;
        float hs3 = (l0 >= 1) ? bf2f(zb[(size_t)(l0 - 1) * DIM_CONV_PAD + 768 + k]) : 0.f;
        float run_re = sums[(size_t)rest * DIM_CONV + 12 + cv];
        float run_im = sums[(size_t)rest * DIM_CONV + 780 + cv];
        for (int i = 0; i < 64; i++) {
            int l = l0 + i;
            float cp = bf2f(zb[(size_t)l * DIM_CONV_PAD + cv]);
            float cs_ = bf2f(zb[(size_t)l * DIM_CONV_PAD + 768 + k]);
            float kv = siluf_(P.wp[0] * hp1 + P.wp[1] * hp2 + P.wp[2] * hp3 + P.wp[3] * cp);
            float s = siluf_(P.ws4[0] * hs1 + P.ws4[1] * hs2 + P.ws4[2] * hs3 + P.ws4[3] * cs_);
            hp1 = hp2; hp2 = hp3; hp3 = cp;
            hs1 = hs2; hs2 = hs3; hs3 = cs_;
            float pw = softplusf_(P.ss * s + P.sb) * expf(-P.slope * (float)(L_SEQ - 1 - l));
            pw = fminf(fmaxf(pw, 1e-4f), 5000.0f);
            float ksv = kv * P.ps;
            float phi = ksv / (1.0f + fabsf(ksv)) * P.theta;
            float sn, cn;
            sincosf(phi, &sn, &cn);
            float kvw = kv * pw;
            run_re += kvw * cn;
            run_im += kvw * sn;
            csb[(size_t)l * CS_LD + 12 + cv] = __float2bfloat16(run_re);
            csb[(size_t)l * CS_LD + 780 + cv] = __float2bfloat16(run_im);
        }
    } else if (cv < 780) {
        int k = cv - 768;
        float w0 = conv_w[0 * DIM_CONV + 768 + k], w1 = conv_w[1 * DIM_CONV + 768 + k];
        float w2 = conv_w[2 * DIM_CONV + 768 + k], w3 = conv_w[3 * DIM_CONV + 768 + k];
        float ss = sscale[k], sb = sbias[k];
        float slope = softplusf_(decay[k]);
        float h1 = (l0 >= 3) ? bf2f(zb[(size_t)(l0 - 3) * DIM_CONV_PAD + 768 + k]) : 0.f;
        float h2 = (l0 >= 2) ? bf2f(zb[(size_t)(l0 - 2) * DIM_CONV_PAD + 768 + k]) : 0.f;
        float h3 = (l0 >= 1) ? bf2f(zb[(size_t)(l0 - 1) * DIM_CONV_PAD + 768 + k]) : 0.f;
        float run = sums[(size_t)rest * DIM_CONV + k];
        for (int i = 0; i < 64; i++) {
            int l = l0 + i;
            float c = bf2f(zb[(size_t)l * DIM_CONV_PAD + 768 + k]);
            float s = siluf_(w0 * h1 + w1 * h2 + w2 * h3 + w3 * c);
            h1 = h2; h2 = h3; h3 = c;
            float pw = softplusf_(ss * s + sb) * expf(-slope * (float)(L_SEQ - 1 - l));
            run += fminf(fmaxf(pw, 1e-4f), 5000.0f);
            csb[(size_t)l * CS_LD + k] = __float2bfloat16(run);
        }
    } else {
        int qc = cv - 780;
        float w0 = conv_w[0 * DIM_CONV + cv], w1 = conv_w[1 * DIM_CONV + cv];
        float w2 = conv_w[2 * DIM_CONV + cv], w3 = conv_w[3 * DIM_CONV + cv];
        float h1 = (l0 >= 3) ? bf2f(zb[(size_t)(l0 - 3) * DIM_CONV_PAD + cv]) : 0.f;
        float h2 = (l0 >= 2) ? bf2f(zb[(size_t)(l0 - 2) * DIM_CONV_PAD + cv]) : 0.f;
        float h3 = (l0 >= 1) ? bf2f(zb[(size_t)(l0 - 1) * DIM_CONV_PAD + cv]) : 0.f;
        for (int i = 0; i < 64; i++) {
            int l = l0 + i;
            float c = bf2f(zb[(size_t)l * DIM_CONV_PAD + cv]);
            float q = siluf_(w0 * h1 + w1 * h2 + w2 * h3 + w3 * c);
            h1 = h2; h2 = h3; h3 = c;
            qbuf[((size_t)(b * L_SEQ + l)) * 768 + qc] = __float2bfloat16(q);
        }
    }
}

// ---------------------------------------------------------------------------
// match + gated RMSNorm. One block per (b,l). Writes out_n IN-PLACE into the
// cs row (cols [0,1536), row stride CS_LD).
// ---------------------------------------------------------------------------
__global__ __launch_bounds__(256) void match_norm_kernel(
    bf16* __restrict__ cs, const bf16* __restrict__ qbuf,
    const bf16* __restrict__ gate, const float* __restrict__ w_int_raw,
    const float* __restrict__ gnw)
{
    const int bl = blockIdx.x;
    bf16* csr = cs + (size_t)bl * CS_LD;
    const bf16* qr = qbuf + (size_t)bl * 768;
    const bf16* gr = gate + (size_t)bl * OUT_CPLX;
    __shared__ float inv_den[NK];
    __shared__ float wsum[4];

    if (threadIdx.x < NK)
        inv_den[threadIdx.x] = 1.0f / fmaxf(bf2f(csr[threadIdx.x]), 1e-4f);
    __syncthreads();

    float vals[6];
    float ss = 0.0f;
#pragma unroll
    for (int it = 0; it < 6; it++) {
        int c = threadIdx.x + it * 256;      // 0..1535
        int k = c >> 7;
        int r = c & 127;
        int h = r & 63;
        bool is_im = (r >= 64);
        int kq = k >> 1;
        float idn = inv_den[k];
        float sre = bf2f(csr[12 + k * 64 + h]) * idn;
        float sim = bf2f(csr[780 + k * 64 + h]) * idn;
        float qre = bf2f(qr[kq * 128 + 2 * h]);
        float qim = bf2f(qr[kq * 128 + 2 * h + 1]);
        float w = expf(w_int_raw[k * 64 + h]);
        w = w / (w + 1e-6f);
        float m = is_im ? (sim * qre - sre * qim) : (sre * qre + sim * qim);
        m *= 0.125f * w;
        float hv = m * siluf_(bf2f(gr[c]));
        vals[it] = hv;
        ss += hv * hv;
    }
    const int lane = threadIdx.x & 63;
    const int wave = threadIdx.x >> 6;
#pragma unroll
    for (int off = 32; off > 0; off >>= 1) ss += __shfl_down(ss, off);
    if (lane == 0) wsum[wave] = ss;
    __syncthreads();
    float total = wsum[0] + wsum[1] + wsum[2] + wsum[3];
    float inv_rms = rsqrtf(total * (1.0f / (float)OUT_CPLX) + 1e-6f);
#pragma unroll
    for (int it = 0; it < 6; it++) {
        int c = threadIdx.x + it * 256;
        csr[c] = __float2bfloat16(vals[it] * inv_rms * gnw[c]);
    }
}

__global__ void sentinel_kernel(float* out, float v)
{
    if (threadIdx.x == 0) out[0] = v;
}

// ---------------------------------------------------------------------------
// Workspace layout (bytes)
// ---------------------------------------------------------------------------
#define XB_OFF 0UL                 // 16384x768 bf16       25,165,824
#define WT_IN_OFF 25165824UL       // 1664x768 bf16         2,555,904
#define WT_GATE_OFF 27721728UL     // 1536x768 bf16         2,359,296
#define WT_OUT_OFF 30081024UL      // 768x2304 bf16         3,538,944
#define WT_RO_OFF 33619968UL       // 12x384x128 bf16       1,179,648
#define SUMS_OFF 34799616UL        // 4x64x1548 fp32        1,585,152
#define CS_OFF 36384768UL          // 16384x1552 bf16      50,855,936 (later holds out_n in-place)
#define A_OFF 87240704UL           // z0 bf16 16384x1664 = 54,525,952; later gate bf16; later y start
#define QBUF_OFF 141766656UL       // 16384x768 bf16       25,165,824 (later tail of y)
#define WS_NEEDED 166932480UL      // ~159.2 MB; y = A_OFF..A_OFF+75,497,472 fits

static inline int cdiv(long n) { return (int)((n + 255) / 256); }

extern "C" void kernel_launch(void* const* d_in, const int* in_sizes, int n_in,
                              void* d_out, int out_size, void* d_ws, size_t ws_size,
                              hipStream_t stream)
{
    const float* x = (const float*)d_in[0];
    const float* W_in = (const float*)d_in[1];
    const float* conv_w = (const float*)d_in[2];
    const float* theta_raw = (const float*)d_in[3];
    const float* w_int_raw = (const float*)d_in[4];
    const float* decay_slopes = (const float*)d_in[5];
    const float* score_scale = (const float*)d_in[6];
    const float* score_bias = (const float*)d_in[7];
    const float* phase_scale = (const float*)d_in[8];
    const float* gnw = (const float*)d_in[9];
    const float* W_readout = (const float*)d_in[10];
    const float* W_gate = (const float*)d_in[11];
    const float* W_out = (const float*)d_in[12];

    if (ws_size < WS_NEEDED) {
        // Diagnostic: reported absmax will approximately equal ws_size.
        sentinel_kernel<<<1, 64, 0, stream>>>((float*)d_out, (float)ws_size);
        return;
    }

    char* ws = (char*)d_ws;
    bf16* xb = (bf16*)(ws + XB_OFF);
    bf16* WT_IN = (bf16*)(ws + WT_IN_OFF);
    bf16* WT_GATE = (bf16*)(ws + WT_GATE_OFF);
    bf16* WT_OUT = (bf16*)(ws + WT_OUT_OFF);
    bf16* WT_RO = (bf16*)(ws + WT_RO_OFF);
    float* sums = (float*)(ws + SUMS_OFF);
    bf16* cs = (bf16*)(ws + CS_OFF);          // cumsum rows; later out_n in-place
    bf16* z0 = (bf16*)(ws + A_OFF);           // 16384x1664
    bf16* gate = (bf16*)(ws + A_OFF);         // 16384x1536 (after z0 dead)
    bf16* y = (bf16*)(ws + A_OFF);            // 16384x2304 (after gate+qbuf dead)
    bf16* qbuf = (bf16*)(ws + QBUF_OFF);      // 16384x768

    // 0. convert x to bf16
    convert_f2b<<<cdiv(16384L * 768 / 4), 256, 0, stream>>>(x, xb, 16384L * 768);

    // 1. weight transposes (fp32 -> bf16)
    transpose_pad_f2b<<<cdiv(1664L * 768), 256, 0, stream>>>(W_in, WT_IN, 768, 1548, 1664);
    transpose_pad_f2b<<<cdiv(1536L * 768), 256, 0, stream>>>(W_gate, WT_GATE, 768, 1536, 1536);
    transpose_pad_f2b<<<cdiv(768L * 2304), 256, 0, stream>>>(W_out, WT_OUT, 2304, 768, 768);
    transpose_ro_f2b<<<cdiv(12L * 384 * 128), 256, 0, stream>>>(W_readout, WT_RO);

    // 2. z0 = x @ W_in (bf16 out, padded N=1664)
    gemm_kernel<true><<<dim3(128, 13), 256, 0, stream>>>(xb, 768, WT_IN, 768, z0, 1664, 768);

    // 3-5. fused conv+transform+chunked scan -> cs (bf16), qbuf
    scan_pass_a_f<<<780, 256, 0, stream>>>(z0, conv_w, theta_raw, decay_slopes,
                                           score_scale, score_bias, phase_scale, sums);
    scan_mid<<<cdiv((long)B_SZ * DIM_CONV), 256, 0, stream>>>(sums);
    scan_pass_c_f<<<1548, 256, 0, stream>>>(z0, conv_w, theta_raw, decay_slopes,
                                            score_scale, score_bias, phase_scale, sums,
                                            cs, qbuf);

    // 6. gate = x @ W_gate (bf16, overwrites z0 region)
    gemm_kernel<true><<<dim3(128, 12), 256, 0, stream>>>(xb, 768, WT_GATE, 768, gate, 1536, 768);

    // 7. match + gated rmsnorm -> out_n in-place into cs rows
    match_norm_kernel<<<NROW, 256, 0, stream>>>(cs, qbuf, gate, w_int_raw, gnw);

    // 8. readout GEMM + fused GLU -> y (bf16, overwrites gate/qbuf regions)
    gemm_readout_glu<<<dim3(128, 3, 12), 256, 0, stream>>>(
        cs, CS_LD, 128L, WT_RO, 128, 49152L, y, 128);

    // 9. out = y @ W_out (fp32 out)
    gemm_kernel<false><<<dim3(128, 6), 256, 0, stream>>>(y, 2304, WT_OUT, 2304,
                                                         (float*)d_out, 768, 2304);
}

// Round 3
// 653.808 us; speedup vs baseline: 1.4114x; 1.4114x over previous
//
#include <hip/hip_runtime.h>
#include <hip/hip_bf16.h>

typedef __hip_bfloat16 bf16;
typedef __attribute__((ext_vector_type(8))) short short8;
typedef __attribute__((ext_vector_type(4))) float floatx4;

#define L_SEQ 4096
#define B_SZ 4
#define NROW 16384          // B*L
#define NK 12
#define HD 64
#define DIM_CONV 1548
#define Z_LD 1552           // z0 row stride (bf16 elems), 16B-aligned
#define OUT_CPLX 1536
#define CS_LD 1552          // cs row stride (bf16 elems), 16B-aligned
#define KSIZE 4

__device__ __forceinline__ float bf2f(bf16 v) { return __bfloat162float(v); }
__device__ __forceinline__ float frcp(float x) { return __builtin_amdgcn_rcpf(x); }
__device__ __forceinline__ float fsigmoid(float x) { return frcp(1.0f + __expf(-x)); }
__device__ __forceinline__ float fsilu(float x) { return x * fsigmoid(x); }
__device__ __forceinline__ float fsoftplus(float x) {
    return fmaxf(x, 0.0f) + __logf(1.0f + __expf(-fabsf(x)));
}

// ---------------------------------------------------------------------------
// bf16 MFMA GEMM: C[M x N] = A[M x Kd] * Bt[N x Kd]^T. 128x128 tile, BK=32.
// LDS chunk q = k8*128 + row holds X[row][k8*8..+8].
//   A frag: A[m=lane&15][k=(lane>>4)*8+j]; B frag: B[k][n=lane&15]
//   C/D:    col=lane&15, row=(lane>>4)*4+reg
// ---------------------------------------------------------------------------
#define GEMM_CORE(A_, lda_, Bt_, ldb_, Kd_)                                              \
    __shared__ __align__(16) short lds_a[4][128][8];                                     \
    __shared__ __align__(16) short lds_b[4][128][8];                                     \
    const int tid = threadIdx.x;                                                         \
    const int wave = tid >> 6;                                                           \
    const int lane = tid & 63;                                                           \
    const int q0 = wave * 64 + lane;                                                     \
    const int q1 = q0 + 256;                                                             \
    const bf16* ga0 = A_ + (size_t)(q0 & 127) * lda_ + ((q0 >> 7) << 3);                 \
    const bf16* ga1 = A_ + (size_t)(q1 & 127) * lda_ + ((q1 >> 7) << 3);                 \
    const bf16* gb0 = Bt_ + (size_t)(q0 & 127) * ldb_ + ((q0 >> 7) << 3);                \
    const bf16* gb1 = Bt_ + (size_t)(q1 & 127) * ldb_ + ((q1 >> 7) << 3);                \
    short* la0 = &lds_a[0][0][0] + wave * 512;                                           \
    short* la1 = &lds_a[0][0][0] + 2048 + wave * 512;                                    \
    short* lb0 = &lds_b[0][0][0] + wave * 512;                                           \
    short* lb1 = &lds_b[0][0][0] + 2048 + wave * 512;                                    \
    floatx4 acc[4][4];                                                                   \
    _Pragma("unroll") for (int i = 0; i < 4; i++)                                        \
        _Pragma("unroll") for (int j = 0; j < 4; j++)                                    \
            acc[i][j] = (floatx4){0.f, 0.f, 0.f, 0.f};                                   \
    const int wm = (wave >> 1) * 64;                                                     \
    const int wn = (wave & 1) * 64;                                                      \
    const int lrow = lane & 15;                                                          \
    const int lk8 = lane >> 4;                                                           \
    for (int k0 = 0; k0 < Kd_; k0 += 32) {                                               \
        __builtin_amdgcn_global_load_lds((const __attribute__((address_space(1))) void*)ga0, \
                                         (__attribute__((address_space(3))) void*)la0, 16, 0, 0); \
        __builtin_amdgcn_global_load_lds((const __attribute__((address_space(1))) void*)ga1, \
                                         (__attribute__((address_space(3))) void*)la1, 16, 0, 0); \
        __builtin_amdgcn_global_load_lds((const __attribute__((address_space(1))) void*)gb0, \
                                         (__attribute__((address_space(3))) void*)lb0, 16, 0, 0); \
        __builtin_amdgcn_global_load_lds((const __attribute__((address_space(1))) void*)gb1, \
                                         (__attribute__((address_space(3))) void*)lb1, 16, 0, 0); \
        ga0 += 32; ga1 += 32; gb0 += 32; gb1 += 32;                                      \
        __syncthreads();                                                                 \
        short8 af[4], bfv[4];                                                            \
        _Pragma("unroll") for (int i = 0; i < 4; i++)                                    \
            af[i] = *(const short8*)(&lds_a[lk8][wm + i * 16 + lrow][0]);                \
        _Pragma("unroll") for (int j = 0; j < 4; j++)                                    \
            bfv[j] = *(const short8*)(&lds_b[lk8][wn + j * 16 + lrow][0]);               \
        _Pragma("unroll") for (int i = 0; i < 4; i++)                                    \
            _Pragma("unroll") for (int j = 0; j < 4; j++)                                \
                acc[i][j] = __builtin_amdgcn_mfma_f32_16x16x32_bf16(af[i], bfv[j], acc[i][j], 0, 0, 0); \
        __syncthreads();                                                                 \
    }

template <bool OUT_BF16>
__global__ __launch_bounds__(256, 2) void gemm_kernel(
    const bf16* __restrict__ A, int lda,
    const bf16* __restrict__ Bt, int ldb,
    void* __restrict__ Cv, int ldc, int Kd, int nmax)
{
    const bf16* Ab = A + (size_t)blockIdx.x * 128 * lda;
    const bf16* Bb = Bt + (size_t)blockIdx.y * 128 * ldb;
    GEMM_CORE(Ab, lda, Bb, ldb, Kd)
    const int orow = blockIdx.x * 128 + wm + (lk8 << 2);
    const int ocol = blockIdx.y * 128 + wn + lrow;
    if (OUT_BF16) {
        bf16* C = (bf16*)Cv;
#pragma unroll
        for (int i = 0; i < 4; i++)
#pragma unroll
            for (int j = 0; j < 4; j++)
                if (ocol + j * 16 < nmax)
#pragma unroll
                    for (int r = 0; r < 4; r++)
                        C[(size_t)(orow + i * 16 + r) * ldc + (ocol + j * 16)] =
                            __float2bfloat16(acc[i][j][r]);
    } else {
        float* C = (float*)Cv;
#pragma unroll
        for (int i = 0; i < 4; i++)
#pragma unroll
            for (int j = 0; j < 4; j++)
                if (ocol + j * 16 < nmax)
#pragma unroll
                    for (int r = 0; r < 4; r++)
                        C[(size_t)(orow + i * 16 + r) * ldc + (ocol + j * 16)] = acc[i][j][r];
    }
}

// Readout GEMM with fused GLU epilogue. Bt columns pair-interleaved:
// paired col 2j = val_j, 2j+1 = gate_j. Even lane gets gate via shfl_xor(1).
__global__ __launch_bounds__(256, 2) void gemm_readout_glu(
    const bf16* __restrict__ A, int lda, long a_zoff,
    const bf16* __restrict__ Bt, int ldb, long b_zoff,
    bf16* __restrict__ Y, int Kd)
{
    const int z = blockIdx.z;
    const bf16* Ab = A + (long)z * a_zoff + (size_t)blockIdx.x * 128 * lda;
    const bf16* Bb = Bt + (long)z * b_zoff + (size_t)blockIdx.y * 128 * ldb;
    GEMM_CORE(Ab, lda, Bb, ldb, Kd)
    const int orow = blockIdx.x * 128 + wm + (lk8 << 2);
    const int pcol0 = blockIdx.y * 128 + wn + lrow;
    const bool is_v = ((lane & 1) == 0);
    bf16* Yk = Y + (long)z * 192;
#pragma unroll
    for (int i = 0; i < 4; i++)
#pragma unroll
        for (int j = 0; j < 4; j++)
#pragma unroll
            for (int r = 0; r < 4; r++) {
                float v = acc[i][j][r];
                float g = __shfl_xor(v, 1);
                float o = v * fsigmoid(g);
                if (is_v)
                    Yk[(size_t)(orow + i * 16 + r) * 2304 + ((pcol0 + j * 16) >> 1)] =
                        __float2bfloat16(o);
            }
}

// ---------------------------------------------------------------------------
// fp32 -> bf16 conversions / weight transposes
// ---------------------------------------------------------------------------
__global__ void convert_f2b(const float* __restrict__ in, bf16* __restrict__ out, long n)
{
    long gid = ((long)blockIdx.x * 256 + threadIdx.x) * 4;
    if (gid >= n) return;
    float4 v = *(const float4*)(in + gid);
    out[gid + 0] = __float2bfloat16(v.x);
    out[gid + 1] = __float2bfloat16(v.y);
    out[gid + 2] = __float2bfloat16(v.z);
    out[gid + 3] = __float2bfloat16(v.w);
}

__global__ void transpose_pad_f2b(const float* __restrict__ in, bf16* __restrict__ out,
                                  int R, int C, int Cp)
{
    long gid = (long)blockIdx.x * 256 + threadIdx.x;
    if (gid >= (long)Cp * R) return;
    int r = (int)(gid % R);
    int n = (int)(gid / R);
    out[gid] = __float2bfloat16((n < C) ? in[(size_t)r * C + n] : 0.0f);
}

// W_readout (12,128,384) fp32 -> WT_RO (12,384,128) bf16, pair-interleaved cols
__global__ void transpose_ro_f2b(const float* __restrict__ in, bf16* __restrict__ out)
{
    long gid = (long)blockIdx.x * 256 + threadIdx.x;
    if (gid >= 12L * 384 * 128) return;
    int f = (int)(gid % 128);
    int rest = (int)(gid / 128);
    int n = rest % 384;
    int k = rest / 384;
    int src = (n & 1) ? (192 + (n >> 1)) : (n >> 1);
    out[gid] = __float2bfloat16(in[((size_t)k * 128 + f) * 384 + src]);
}

// w_int table: wtab[i] = e^w / (e^w + 1e-6)
__global__ void prep_wint(const float* __restrict__ w_raw, float* __restrict__ wtab)
{
    int i = blockIdx.x * 256 + threadIdx.x;
    if (i >= 768) return;
    float e = __expf(w_raw[i]);
    wtab[i] = e * frcp(e + 1e-6f);
}

// ---------------------------------------------------------------------------
// pw_kernel: p_w[b][l][k] computed ONCE (score conv + softplus + decay + clip).
// Thread = (b, chunk, k), rolling 4-tap window over 64 positions.
// ---------------------------------------------------------------------------
__global__ __launch_bounds__(256) void pw_kernel(
    const bf16* __restrict__ z0, const float* __restrict__ conv_w,
    const float* __restrict__ decay, const float* __restrict__ sscale,
    const float* __restrict__ sbias, float* __restrict__ pw_buf)
{
    int gid = blockIdx.x * 256 + threadIdx.x;
    if (gid >= B_SZ * 64 * NK) return;
    int k = gid % NK;
    int rest = gid / NK;          // b*64 + chunk
    int chunk = rest & 63;
    int b = rest >> 6;
    int l0 = chunk * 64;
    const int c = 768 + k;
    const bf16* zb = z0 + (size_t)b * L_SEQ * Z_LD;
    float w0 = conv_w[0 * DIM_CONV + c], w1 = conv_w[1 * DIM_CONV + c];
    float w2 = conv_w[2 * DIM_CONV + c], w3 = conv_w[3 * DIM_CONV + c];
    float ss = sscale[k], sb = sbias[k];
    float slope = fsoftplus(decay[k]);
    float h1 = (l0 >= 3) ? bf2f(zb[(size_t)(l0 - 3) * Z_LD + c]) : 0.f;
    float h2 = (l0 >= 2) ? bf2f(zb[(size_t)(l0 - 2) * Z_LD + c]) : 0.f;
    float h3 = (l0 >= 1) ? bf2f(zb[(size_t)(l0 - 1) * Z_LD + c]) : 0.f;
    for (int i = 0; i < 64; i++) {
        int l = l0 + i;
        float cur = bf2f(zb[(size_t)l * Z_LD + c]);
        float s = fsilu(w0 * h1 + w1 * h2 + w2 * h3 + w3 * cur);
        h1 = h2; h2 = h3; h3 = cur;
        float pw = fsoftplus(ss * s + sb) * __expf(-slope * (float)(L_SEQ - 1 - l));
        pw = fminf(fmaxf(pw, 1e-4f), 5000.0f);
        pw_buf[((size_t)(b * L_SEQ + l)) * NK + k] = pw;
    }
}

// ---------------------------------------------------------------------------
// scan_terms: compute per-position terms ONCE, write bf16 into cs + qbuf,
// accumulate per-chunk sums FROM THE ROUNDED terms (bit-consistent w/ pass C).
// cs cols: [0,12)=pw(k), [12,780)=re(cv), [780,1548)=im(cv).
// ---------------------------------------------------------------------------
__global__ __launch_bounds__(256) void scan_terms(
    const bf16* __restrict__ z0, const float* __restrict__ conv_w,
    const float* __restrict__ theta_raw, const float* __restrict__ pscale,
    const float* __restrict__ pw_buf,
    bf16* __restrict__ cs, bf16* __restrict__ qbuf, float* __restrict__ sums)
{
    int gid = blockIdx.x * 256 + threadIdx.x;
    if (gid >= B_SZ * 64 * DIM_CONV) return;
    int cv = gid % DIM_CONV;
    int rest = gid / DIM_CONV;    // b*64 + chunk
    int chunk = rest & 63;
    int b = rest >> 6;
    int l0 = chunk * 64;
    const bf16* zb = z0 + (size_t)b * L_SEQ * Z_LD;
    bf16* csb = cs + (size_t)b * L_SEQ * CS_LD;
    const size_t bL = (size_t)b * L_SEQ;

    if (cv < 768) {
        int k = cv >> 6;
        float w0 = conv_w[0 * DIM_CONV + cv], w1 = conv_w[1 * DIM_CONV + cv];
        float w2 = conv_w[2 * DIM_CONV + cv], w3 = conv_w[3 * DIM_CONV + cv];
        float theta = 0.001f + 2.999f * fsigmoid(theta_raw[cv]);
        float ps = pscale[k];
        float h1 = (l0 >= 3) ? bf2f(zb[(size_t)(l0 - 3) * Z_LD + cv]) : 0.f;
        float h2 = (l0 >= 2) ? bf2f(zb[(size_t)(l0 - 2) * Z_LD + cv]) : 0.f;
        float h3 = (l0 >= 1) ? bf2f(zb[(size_t)(l0 - 1) * Z_LD + cv]) : 0.f;
        float sum_re = 0.f, sum_im = 0.f;
        for (int i = 0; i < 64; i++) {
            int l = l0 + i;
            float cur = bf2f(zb[(size_t)l * Z_LD + cv]);
            float kv = fsilu(w0 * h1 + w1 * h2 + w2 * h3 + w3 * cur);
            h1 = h2; h2 = h3; h3 = cur;
            float pw = pw_buf[(bL + l) * NK + k];     // wave-broadcast load
            float ksv = kv * ps;
            float phi = ksv * frcp(1.0f + fabsf(ksv)) * theta;
            float sn = __sinf(phi);
            float cn = __cosf(phi);
            float kvw = kv * pw;
            bf16 tr = __float2bfloat16(kvw * cn);
            bf16 ti = __float2bfloat16(kvw * sn);
            csb[(size_t)l * CS_LD + 12 + cv] = tr;
            csb[(size_t)l * CS_LD + 780 + cv] = ti;
            sum_re += bf2f(tr);
            sum_im += bf2f(ti);
        }
        sums[(size_t)rest * DIM_CONV + 12 + cv] = sum_re;
        sums[(size_t)rest * DIM_CONV + 780 + cv] = sum_im;
    } else if (cv < 780) {
        int k = cv - 768;
        float sum_pw = 0.f;
        for (int i = 0; i < 64; i++) {
            int l = l0 + i;
            bf16 t = __float2bfloat16(pw_buf[(bL + l) * NK + k]);
            csb[(size_t)l * CS_LD + k] = t;
            sum_pw += bf2f(t);
        }
        sums[(size_t)rest * DIM_CONV + k] = sum_pw;
    } else {
        int qc = cv - 780;
        float w0 = conv_w[0 * DIM_CONV + cv], w1 = conv_w[1 * DIM_CONV + cv];
        float w2 = conv_w[2 * DIM_CONV + cv], w3 = conv_w[3 * DIM_CONV + cv];
        float h1 = (l0 >= 3) ? bf2f(zb[(size_t)(l0 - 3) * Z_LD + cv]) : 0.f;
        float h2 = (l0 >= 2) ? bf2f(zb[(size_t)(l0 - 2) * Z_LD + cv]) : 0.f;
        float h3 = (l0 >= 1) ? bf2f(zb[(size_t)(l0 - 1) * Z_LD + cv]) : 0.f;
        for (int i = 0; i < 64; i++) {
            int l = l0 + i;
            float cur = bf2f(zb[(size_t)l * Z_LD + cv]);
            float q = fsilu(w0 * h1 + w1 * h2 + w2 * h3 + w3 * cur);
            h1 = h2; h2 = h3; h3 = cur;
            qbuf[(bL + l) * 768 + qc] = __float2bfloat16(q);
        }
    }
}

// chunk-sum exclusive scan over 64 chunks, per (b, col)
__global__ void scan_mid(float* __restrict__ sums)
{
    int gid = blockIdx.x * 256 + threadIdx.x;
    if (gid >= B_SZ * DIM_CONV) return;
    int c = gid % DIM_CONV;
    int b = gid / DIM_CONV;
    float run = 0.f;
    for (int i = 0; i < 64; i++) {
        size_t idx = ((size_t)(b * 64 + i)) * DIM_CONV + c;
        float v = sums[idx];
        sums[idx] = run;
        run += v;
    }
}

// in-place cumsum: run (fp32) over bf16 terms, write back bf16
__global__ __launch_bounds__(256) void scan_inplace(
    bf16* __restrict__ cs, const float* __restrict__ sums)
{
    int gid = blockIdx.x * 256 + threadIdx.x;
    if (gid >= B_SZ * 64 * DIM_CONV) return;
    int c = gid % DIM_CONV;
    int rest = gid / DIM_CONV;
    int chunk = rest & 63;
    int b = rest >> 6;
    float run = sums[(size_t)rest * DIM_CONV + c];
    bf16* p = cs + ((size_t)(b * L_SEQ + chunk * 64)) * CS_LD + c;
    for (int i = 0; i < 64; i++) {
        run += bf2f(p[0]);
        p[0] = __float2bfloat16(run);
        p += CS_LD;
    }
}

// ---------------------------------------------------------------------------
// match + gated RMSNorm. One block per (b,l). Writes out_n IN-PLACE into the
// cs row (cols [0,1536), row stride CS_LD).
// ---------------------------------------------------------------------------
__global__ __launch_bounds__(256) void match_norm_kernel(
    bf16* __restrict__ cs, const bf16* __restrict__ qbuf,
    const bf16* __restrict__ gate, const float* __restrict__ wtab,
    const float* __restrict__ gnw)
{
    const int bl = blockIdx.x;
    bf16* csr = cs + (size_t)bl * CS_LD;
    const bf16* qr = qbuf + (size_t)bl * 768;
    const bf16* gr = gate + (size_t)bl * OUT_CPLX;
    __shared__ float inv_den[NK];
    __shared__ float wsum[4];

    if (threadIdx.x < NK)
        inv_den[threadIdx.x] = 1.0f / fmaxf(bf2f(csr[threadIdx.x]), 1e-4f);
    __syncthreads();

    float vals[6];
    float ss = 0.0f;
#pragma unroll
    for (int it = 0; it < 6; it++) {
        int c = threadIdx.x + it * 256;      // 0..1535
        int k = c >> 7;
        int r = c & 127;
        int h = r & 63;
        bool is_im = (r >= 64);
        int kq = k >> 1;
        float idn = inv_den[k];
        float sre = bf2f(csr[12 + k * 64 + h]) * idn;
        float sim = bf2f(csr[780 + k * 64 + h]) * idn;
        float qre = bf2f(qr[kq * 128 + 2 * h]);
        float qim = bf2f(qr[kq * 128 + 2 * h + 1]);
        float w = wtab[k * 64 + h];
        float m = is_im ? (sim * qre - sre * qim) : (sre * qre + sim * qim);
        m *= 0.125f * w;
        float hv = m * fsilu(bf2f(gr[c]));
        vals[it] = hv;
        ss += hv * hv;
    }
    const int lane = threadIdx.x & 63;
    const int wave = threadIdx.x >> 6;
#pragma unroll
    for (int off = 32; off > 0; off >>= 1) ss += __shfl_down(ss, off);
    if (lane == 0) wsum[wave] = ss;
    __syncthreads();
    float total = wsum[0] + wsum[1] + wsum[2] + wsum[3];
    float inv_rms = rsqrtf(total * (1.0f / (float)OUT_CPLX) + 1e-6f);
#pragma unroll
    for (int it = 0; it < 6; it++) {
        int c = threadIdx.x + it * 256;
        csr[c] = __float2bfloat16(vals[it] * inv_rms * gnw[c]);
    }
}

__global__ void sentinel_kernel(float* out, float v)
{
    if (threadIdx.x == 0) out[0] = v;
}

// ---------------------------------------------------------------------------
// Workspace layout (bytes)
// ---------------------------------------------------------------------------
#define XB_OFF 0UL                 // 16384x768 bf16       25,165,824
#define WT_IN_OFF 25165824UL       // 1664x768 bf16         2,555,904
#define WT_GATE_OFF 27721728UL     // 1536x768 bf16         2,359,296
#define WT_OUT_OFF 30081024UL      // 768x2304 bf16         3,538,944
#define WT_RO_OFF 33619968UL       // 12x384x128 bf16       1,179,648
#define SUMS_OFF 34799616UL        // 4x64x1548 fp32        1,585,152
#define PW_OFF 36384768UL          // 16384x12 fp32           786,432
#define WTAB_OFF 37171200UL        // 768 fp32                  3,072
#define CS_OFF 37174272UL          // 16384x1552 bf16      50,855,936
#define A_OFF 88030208UL           // z0 (16384x1552 bf16 = 50,855,936); later gate; later y (75,497,472)
#define QBUF_OFF 138886144UL       // 16384x768 bf16       25,165,824 (later overlapped by y tail)
#define WS_NEEDED 164051968UL      // proven available >= 166,932,480 in round 2

static inline int cdiv(long n) { return (int)((n + 255) / 256); }

extern "C" void kernel_launch(void* const* d_in, const int* in_sizes, int n_in,
                              void* d_out, int out_size, void* d_ws, size_t ws_size,
                              hipStream_t stream)
{
    const float* x = (const float*)d_in[0];
    const float* W_in = (const float*)d_in[1];
    const float* conv_w = (const float*)d_in[2];
    const float* theta_raw = (const float*)d_in[3];
    const float* w_int_raw = (const float*)d_in[4];
    const float* decay_slopes = (const float*)d_in[5];
    const float* score_scale = (const float*)d_in[6];
    const float* score_bias = (const float*)d_in[7];
    const float* phase_scale = (const float*)d_in[8];
    const float* gnw = (const float*)d_in[9];
    const float* W_readout = (const float*)d_in[10];
    const float* W_gate = (const float*)d_in[11];
    const float* W_out = (const float*)d_in[12];

    if (ws_size < WS_NEEDED) {
        sentinel_kernel<<<1, 64, 0, stream>>>((float*)d_out, (float)ws_size);
        return;
    }

    char* ws = (char*)d_ws;
    bf16* xb = (bf16*)(ws + XB_OFF);
    bf16* WT_IN = (bf16*)(ws + WT_IN_OFF);
    bf16* WT_GATE = (bf16*)(ws + WT_GATE_OFF);
    bf16* WT_OUT = (bf16*)(ws + WT_OUT_OFF);
    bf16* WT_RO = (bf16*)(ws + WT_RO_OFF);
    float* sums = (float*)(ws + SUMS_OFF);
    float* pw_buf = (float*)(ws + PW_OFF);
    float* wtab = (float*)(ws + WTAB_OFF);
    bf16* cs = (bf16*)(ws + CS_OFF);
    bf16* z0 = (bf16*)(ws + A_OFF);           // 16384x1552
    bf16* gate = (bf16*)(ws + A_OFF);         // 16384x1536 (after z0 dead)
    bf16* y = (bf16*)(ws + A_OFF);            // 16384x2304 (after gate+qbuf dead)
    bf16* qbuf = (bf16*)(ws + QBUF_OFF);      // 16384x768

    // 0. convert x to bf16; weight prep
    convert_f2b<<<cdiv(16384L * 768 / 4), 256, 0, stream>>>(x, xb, 16384L * 768);
    transpose_pad_f2b<<<cdiv(1664L * 768), 256, 0, stream>>>(W_in, WT_IN, 768, 1548, 1664);
    transpose_pad_f2b<<<cdiv(1536L * 768), 256, 0, stream>>>(W_gate, WT_GATE, 768, 1536, 1536);
    transpose_pad_f2b<<<cdiv(768L * 2304), 256, 0, stream>>>(W_out, WT_OUT, 2304, 768, 768);
    transpose_ro_f2b<<<cdiv(12L * 384 * 128), 256, 0, stream>>>(W_readout, WT_RO);
    prep_wint<<<3, 256, 0, stream>>>(w_int_raw, wtab);

    // 1. z0 = x @ W_in (bf16 out, ldc 1552, cols clipped at 1548)
    gemm_kernel<true><<<dim3(128, 13), 256, 0, stream>>>(xb, 768, WT_IN, 768, z0, Z_LD, 768, 1548);

    // 2. p_w table (computed once)
    pw_kernel<<<12, 256, 0, stream>>>(z0, conv_w, decay_slopes, score_scale, score_bias, pw_buf);

    // 3. terms -> cs/qbuf + chunk sums; chunk scan; in-place cumsum
    scan_terms<<<1548, 256, 0, stream>>>(z0, conv_w, theta_raw, phase_scale, pw_buf,
                                         cs, qbuf, sums);
    scan_mid<<<cdiv((long)B_SZ * DIM_CONV), 256, 0, stream>>>(sums);
    scan_inplace<<<1548, 256, 0, stream>>>(cs, sums);

    // 4. gate = x @ W_gate (bf16, overwrites z0 region)
    gemm_kernel<true><<<dim3(128, 12), 256, 0, stream>>>(xb, 768, WT_GATE, 768, gate, 1536, 768, 1536);

    // 5. match + gated rmsnorm -> out_n in-place into cs rows
    match_norm_kernel<<<NROW, 256, 0, stream>>>(cs, qbuf, gate, wtab, gnw);

    // 6. readout GEMM + fused GLU -> y (bf16)
    gemm_readout_glu<<<dim3(128, 3, 12), 256, 0, stream>>>(
        cs, CS_LD, 128L, WT_RO, 128, 49152L, y, 128);

    // 7. out = y @ W_out (fp32 out)
    gemm_kernel<false><<<dim3(128, 6), 256, 0, stream>>>(y, 2304, WT_OUT, 2304,
                                                         (float*)d_out, 768, 2304, 768);
}

// Round 4
// 495.504 us; speedup vs baseline: 1.8623x; 1.3195x over previous
//
#include <hip/hip_runtime.h>
#include <hip/hip_bf16.h>

typedef __hip_bfloat16 bf16;
typedef __attribute__((ext_vector_type(8))) short short8;
typedef __attribute__((ext_vector_type(4))) float floatx4;

#define L_SEQ 4096
#define B_SZ 4
#define NROW 16384          // B*L
#define NK 12
#define HD 64
#define DIM_CONV 1548
#define Z_LD 1552           // z0 row stride (bf16 elems), 16B-aligned
#define OUT_CPLX 1536
#define CS_LD 1552          // cs row stride (bf16 elems), 16B-aligned
#define KSIZE 4

__device__ __forceinline__ float bf2f(bf16 v) { return __bfloat162float(v); }
__device__ __forceinline__ float frcp(float x) { return __builtin_amdgcn_rcpf(x); }
__device__ __forceinline__ float fsigmoid(float x) { return frcp(1.0f + __expf(-x)); }
__device__ __forceinline__ float fsilu(float x) { return x * fsigmoid(x); }
__device__ __forceinline__ float fsoftplus(float x) {
    return fmaxf(x, 0.0f) + __logf(1.0f + __expf(-fabsf(x)));
}

// ---------------------------------------------------------------------------
// bf16 MFMA GEMM v2: C[M x N] = A[M x Kd] * Bt[N x Kd]^T. 128x128 tile, BK=64.
// LDS layout: position p = row*8 + (k8 ^ (row&7)), 16B chunks (XOR swizzle).
//  - staging: lane l -> row = l>>3, k8 = (l&7)^(row&7): each 8-lane group reads
//    ONE contiguous 128B line -> fully coalesced global_load_lds (8 lines/wave).
//  - ds_read_b128 frag: bank base 4*(k8L^(m&7)) is a bijection over lanes 0..7
//    -> 32 banks covered, lanes 8..15 2-way alias (free). Conflict-free.
//   A frag: A[m=lane&15][k = s2*32 + (lane>>4)*8 + j]; B frag same with n.
//   C/D: col=lane&15, row=(lane>>4)*4+reg
// ---------------------------------------------------------------------------
#define GEMM_CORE2(A_, lda_, Bt_, ldb_, Kd_)                                             \
    __shared__ __align__(16) short lds_a[128 * 64];                                      \
    __shared__ __align__(16) short lds_b[128 * 64];                                      \
    const int tid = threadIdx.x;                                                         \
    const int wave = tid >> 6;                                                           \
    const int lane = tid & 63;                                                           \
    const bf16* ga[4];                                                                   \
    const bf16* gb[4];                                                                   \
    short* la[4];                                                                        \
    short* lb[4];                                                                        \
    _Pragma("unroll") for (int s = 0; s < 4; s++) {                                      \
        int p = s * 256 + wave * 64 + lane;                                              \
        int row = p >> 3;                                                                \
        int k8 = (p & 7) ^ (row & 7);                                                    \
        ga[s] = A_ + (size_t)row * lda_ + k8 * 8;                                        \
        gb[s] = Bt_ + (size_t)row * ldb_ + k8 * 8;                                       \
        la[s] = lds_a + (size_t)(s * 256 + wave * 64) * 8;                               \
        lb[s] = lds_b + (size_t)(s * 256 + wave * 64) * 8;                               \
    }                                                                                    \
    floatx4 acc[4][4];                                                                   \
    _Pragma("unroll") for (int i = 0; i < 4; i++)                                        \
        _Pragma("unroll") for (int j = 0; j < 4; j++)                                    \
            acc[i][j] = (floatx4){0.f, 0.f, 0.f, 0.f};                                   \
    const int wm = (wave >> 1) * 64;                                                     \
    const int wn = (wave & 1) * 64;                                                      \
    const int lrow = lane & 15;                                                          \
    const int lk8 = lane >> 4;                                                           \
    for (int k0 = 0; k0 < Kd_; k0 += 64) {                                               \
        _Pragma("unroll") for (int s = 0; s < 4; s++) {                                  \
            __builtin_amdgcn_global_load_lds((const __attribute__((address_space(1))) void*)ga[s], \
                                             (__attribute__((address_space(3))) void*)la[s], 16, 0, 0); \
            __builtin_amdgcn_global_load_lds((const __attribute__((address_space(1))) void*)gb[s], \
                                             (__attribute__((address_space(3))) void*)lb[s], 16, 0, 0); \
            ga[s] += 64; gb[s] += 64;                                                    \
        }                                                                                \
        __syncthreads();                                                                 \
        _Pragma("unroll") for (int s2 = 0; s2 < 2; s2++) {                               \
            short8 af[4], bfv[4];                                                        \
            const int k8L = s2 * 4 + lk8;                                                \
            _Pragma("unroll") for (int i = 0; i < 4; i++) {                              \
                int m = wm + i * 16 + lrow;                                              \
                af[i] = *(const short8*)(lds_a + ((size_t)m * 8 + (k8L ^ (m & 7))) * 8); \
            }                                                                            \
            _Pragma("unroll") for (int j = 0; j < 4; j++) {                              \
                int n = wn + j * 16 + lrow;                                              \
                bfv[j] = *(const short8*)(lds_b + ((size_t)n * 8 + (k8L ^ (n & 7))) * 8); \
            }                                                                            \
            _Pragma("unroll") for (int i = 0; i < 4; i++)                                \
                _Pragma("unroll") for (int j = 0; j < 4; j++)                            \
                    acc[i][j] = __builtin_amdgcn_mfma_f32_16x16x32_bf16(af[i], bfv[j], acc[i][j], 0, 0, 0); \
        }                                                                                \
        __syncthreads();                                                                 \
    }

template <bool OUT_BF16>
__global__ __launch_bounds__(256, 2) void gemm_kernel(
    const bf16* __restrict__ A, int lda,
    const bf16* __restrict__ Bt, int ldb,
    void* __restrict__ Cv, int ldc, int Kd, int nmax)
{
    const bf16* Ab = A + (size_t)blockIdx.x * 128 * lda;
    const bf16* Bb = Bt + (size_t)blockIdx.y * 128 * ldb;
    GEMM_CORE2(Ab, lda, Bb, ldb, Kd)
    const int orow = blockIdx.x * 128 + wm + (lk8 << 2);
    const int ocol = blockIdx.y * 128 + wn + lrow;
    if (OUT_BF16) {
        bf16* C = (bf16*)Cv;
#pragma unroll
        for (int i = 0; i < 4; i++)
#pragma unroll
            for (int j = 0; j < 4; j++)
                if (ocol + j * 16 < nmax)
#pragma unroll
                    for (int r = 0; r < 4; r++)
                        C[(size_t)(orow + i * 16 + r) * ldc + (ocol + j * 16)] =
                            __float2bfloat16(acc[i][j][r]);
    } else {
        float* C = (float*)Cv;
#pragma unroll
        for (int i = 0; i < 4; i++)
#pragma unroll
            for (int j = 0; j < 4; j++)
                if (ocol + j * 16 < nmax)
#pragma unroll
                    for (int r = 0; r < 4; r++)
                        C[(size_t)(orow + i * 16 + r) * ldc + (ocol + j * 16)] = acc[i][j][r];
    }
}

// Readout GEMM with fused GLU epilogue. Bt columns pair-interleaved:
// paired col 2j = val_j, 2j+1 = gate_j. Even lane gets gate via shfl_xor(1).
__global__ __launch_bounds__(256, 2) void gemm_readout_glu(
    const bf16* __restrict__ A, int lda, long a_zoff,
    const bf16* __restrict__ Bt, int ldb, long b_zoff,
    bf16* __restrict__ Y, int Kd)
{
    const int z = blockIdx.z;
    const bf16* Ab = A + (long)z * a_zoff + (size_t)blockIdx.x * 128 * lda;
    const bf16* Bb = Bt + (long)z * b_zoff + (size_t)blockIdx.y * 128 * ldb;
    GEMM_CORE2(Ab, lda, Bb, ldb, Kd)
    const int orow = blockIdx.x * 128 + wm + (lk8 << 2);
    const int pcol0 = blockIdx.y * 128 + wn + lrow;
    const bool is_v = ((lane & 1) == 0);
    bf16* Yk = Y + (long)z * 192;
#pragma unroll
    for (int i = 0; i < 4; i++)
#pragma unroll
        for (int j = 0; j < 4; j++)
#pragma unroll
            for (int r = 0; r < 4; r++) {
                float v = acc[i][j][r];
                float g = __shfl_xor(v, 1);
                float o = v * fsigmoid(g);
                if (is_v)
                    Yk[(size_t)(orow + i * 16 + r) * 2304 + ((pcol0 + j * 16) >> 1)] =
                        __float2bfloat16(o);
            }
}

// ---------------------------------------------------------------------------
// fp32 -> bf16 conversions / weight transposes
// ---------------------------------------------------------------------------
__global__ void convert_f2b(const float* __restrict__ in, bf16* __restrict__ out, long n)
{
    long gid = ((long)blockIdx.x * 256 + threadIdx.x) * 4;
    if (gid >= n) return;
    float4 v = *(const float4*)(in + gid);
    out[gid + 0] = __float2bfloat16(v.x);
    out[gid + 1] = __float2bfloat16(v.y);
    out[gid + 2] = __float2bfloat16(v.z);
    out[gid + 3] = __float2bfloat16(v.w);
}

__global__ void transpose_pad_f2b(const float* __restrict__ in, bf16* __restrict__ out,
                                  int R, int C, int Cp)
{
    long gid = (long)blockIdx.x * 256 + threadIdx.x;
    if (gid >= (long)Cp * R) return;
    int r = (int)(gid % R);
    int n = (int)(gid / R);
    out[gid] = __float2bfloat16((n < C) ? in[(size_t)r * C + n] : 0.0f);
}

// W_readout (12,128,384) fp32 -> WT_RO (12,384,128) bf16, pair-interleaved cols
__global__ void transpose_ro_f2b(const float* __restrict__ in, bf16* __restrict__ out)
{
    long gid = (long)blockIdx.x * 256 + threadIdx.x;
    if (gid >= 12L * 384 * 128) return;
    int f = (int)(gid % 128);
    int rest = (int)(gid / 128);
    int n = rest % 384;
    int k = rest / 384;
    int src = (n & 1) ? (192 + (n >> 1)) : (n >> 1);
    out[gid] = __float2bfloat16(in[((size_t)k * 128 + f) * 384 + src]);
}

// w_int table: wtab[i] = e^w / (e^w + 1e-6)
__global__ void prep_wint(const float* __restrict__ w_raw, float* __restrict__ wtab)
{
    int i = blockIdx.x * 256 + threadIdx.x;
    if (i >= 768) return;
    float e = __expf(w_raw[i]);
    wtab[i] = e * frcp(e + 1e-6f);
}

// ---------------------------------------------------------------------------
// pw_kernel: p_w[b][l][k] computed ONCE (score conv + softplus + decay + clip).
// ---------------------------------------------------------------------------
__global__ __launch_bounds__(256) void pw_kernel(
    const bf16* __restrict__ z0, const float* __restrict__ conv_w,
    const float* __restrict__ decay, const float* __restrict__ sscale,
    const float* __restrict__ sbias, float* __restrict__ pw_buf)
{
    int gid = blockIdx.x * 256 + threadIdx.x;
    if (gid >= B_SZ * 64 * NK) return;
    int k = gid % NK;
    int rest = gid / NK;          // b*64 + chunk
    int chunk = rest & 63;
    int b = rest >> 6;
    int l0 = chunk * 64;
    const int c = 768 + k;
    const bf16* zb = z0 + (size_t)b * L_SEQ * Z_LD;
    float w0 = conv_w[0 * DIM_CONV + c], w1 = conv_w[1 * DIM_CONV + c];
    float w2 = conv_w[2 * DIM_CONV + c], w3 = conv_w[3 * DIM_CONV + c];
    float ss = sscale[k], sb = sbias[k];
    float slope = fsoftplus(decay[k]);
    float h1 = (l0 >= 3) ? bf2f(zb[(size_t)(l0 - 3) * Z_LD + c]) : 0.f;
    float h2 = (l0 >= 2) ? bf2f(zb[(size_t)(l0 - 2) * Z_LD + c]) : 0.f;
    float h3 = (l0 >= 1) ? bf2f(zb[(size_t)(l0 - 1) * Z_LD + c]) : 0.f;
    for (int i = 0; i < 64; i++) {
        int l = l0 + i;
        float cur = bf2f(zb[(size_t)l * Z_LD + c]);
        float s = fsilu(w0 * h1 + w1 * h2 + w2 * h3 + w3 * cur);
        h1 = h2; h2 = h3; h3 = cur;
        float pw = fsoftplus(ss * s + sb) * __expf(-slope * (float)(L_SEQ - 1 - l));
        pw = fminf(fmaxf(pw, 1e-4f), 5000.0f);
        pw_buf[((size_t)(b * L_SEQ + l)) * NK + k] = pw;
    }
}

// ---------------------------------------------------------------------------
// scan_terms: compute per-position terms ONCE, write bf16 into cs + qbuf,
// accumulate per-chunk sums FROM THE ROUNDED terms (bit-consistent w/ scan).
// cs cols: [0,12)=pw(k), [12,780)=re(cv), [780,1548)=im(cv).
// ---------------------------------------------------------------------------
__global__ __launch_bounds__(256) void scan_terms(
    const bf16* __restrict__ z0, const float* __restrict__ conv_w,
    const float* __restrict__ theta_raw, const float* __restrict__ pscale,
    const float* __restrict__ pw_buf,
    bf16* __restrict__ cs, bf16* __restrict__ qbuf, float* __restrict__ sums)
{
    int gid = blockIdx.x * 256 + threadIdx.x;
    if (gid >= B_SZ * 64 * DIM_CONV) return;
    int cv = gid % DIM_CONV;
    int rest = gid / DIM_CONV;    // b*64 + chunk
    int chunk = rest & 63;
    int b = rest >> 6;
    int l0 = chunk * 64;
    const bf16* zb = z0 + (size_t)b * L_SEQ * Z_LD;
    bf16* csb = cs + (size_t)b * L_SEQ * CS_LD;
    const size_t bL = (size_t)b * L_SEQ;

    if (cv < 768) {
        int k = cv >> 6;
        float w0 = conv_w[0 * DIM_CONV + cv], w1 = conv_w[1 * DIM_CONV + cv];
        float w2 = conv_w[2 * DIM_CONV + cv], w3 = conv_w[3 * DIM_CONV + cv];
        float theta = 0.001f + 2.999f * fsigmoid(theta_raw[cv]);
        float ps = pscale[k];
        float h1 = (l0 >= 3) ? bf2f(zb[(size_t)(l0 - 3) * Z_LD + cv]) : 0.f;
        float h2 = (l0 >= 2) ? bf2f(zb[(size_t)(l0 - 2) * Z_LD + cv]) : 0.f;
        float h3 = (l0 >= 1) ? bf2f(zb[(size_t)(l0 - 1) * Z_LD + cv]) : 0.f;
        float sum_re = 0.f, sum_im = 0.f;
        for (int i = 0; i < 64; i++) {
            int l = l0 + i;
            float cur = bf2f(zb[(size_t)l * Z_LD + cv]);
            float kv = fsilu(w0 * h1 + w1 * h2 + w2 * h3 + w3 * cur);
            h1 = h2; h2 = h3; h3 = cur;
            float pw = pw_buf[(bL + l) * NK + k];     // wave-broadcast load
            float ksv = kv * ps;
            float phi = ksv * frcp(1.0f + fabsf(ksv)) * theta;
            float sn = __sinf(phi);
            float cn = __cosf(phi);
            float kvw = kv * pw;
            bf16 tr = __float2bfloat16(kvw * cn);
            bf16 ti = __float2bfloat16(kvw * sn);
            csb[(size_t)l * CS_LD + 12 + cv] = tr;
            csb[(size_t)l * CS_LD + 780 + cv] = ti;
            sum_re += bf2f(tr);
            sum_im += bf2f(ti);
        }
        sums[(size_t)rest * DIM_CONV + 12 + cv] = sum_re;
        sums[(size_t)rest * DIM_CONV + 780 + cv] = sum_im;
    } else if (cv < 780) {
        int k = cv - 768;
        float sum_pw = 0.f;
        for (int i = 0; i < 64; i++) {
            int l = l0 + i;
            bf16 t = __float2bfloat16(pw_buf[(bL + l) * NK + k]);
            csb[(size_t)l * CS_LD + k] = t;
            sum_pw += bf2f(t);
        }
        sums[(size_t)rest * DIM_CONV + k] = sum_pw;
    } else {
        int qc = cv - 780;
        float w0 = conv_w[0 * DIM_CONV + cv], w1 = conv_w[1 * DIM_CONV + cv];
        float w2 = conv_w[2 * DIM_CONV + cv], w3 = conv_w[3 * DIM_CONV + cv];
        float h1 = (l0 >= 3) ? bf2f(zb[(size_t)(l0 - 3) * Z_LD + cv]) : 0.f;
        float h2 = (l0 >= 2) ? bf2f(zb[(size_t)(l0 - 2) * Z_LD + cv]) : 0.f;
        float h3 = (l0 >= 1) ? bf2f(zb[(size_t)(l0 - 1) * Z_LD + cv]) : 0.f;
        for (int i = 0; i < 64; i++) {
            int l = l0 + i;
            float cur = bf2f(zb[(size_t)l * Z_LD + cv]);
            float q = fsilu(w0 * h1 + w1 * h2 + w2 * h3 + w3 * cur);
            h1 = h2; h2 = h3; h3 = cur;
            qbuf[(bL + l) * 768 + qc] = __float2bfloat16(q);
        }
    }
}

// chunk-sum exclusive scan over 64 chunks, per (b, col)
__global__ void scan_mid(float* __restrict__ sums)
{
    int gid = blockIdx.x * 256 + threadIdx.x;
    if (gid >= B_SZ * DIM_CONV) return;
    int c = gid % DIM_CONV;
    int b = gid / DIM_CONV;
    float run = 0.f;
    for (int i = 0; i < 64; i++) {
        size_t idx = ((size_t)(b * 64 + i)) * DIM_CONV + c;
        float v = sums[idx];
        sums[idx] = run;
        run += v;
    }
}

// in-place cumsum: run (fp32) over bf16 terms, write back bf16
__global__ __launch_bounds__(256) void scan_inplace(
    bf16* __restrict__ cs, const float* __restrict__ sums)
{
    int gid = blockIdx.x * 256 + threadIdx.x;
    if (gid >= B_SZ * 64 * DIM_CONV) return;
    int c = gid % DIM_CONV;
    int rest = gid / DIM_CONV;
    int chunk = rest & 63;
    int b = rest >> 6;
    float run = sums[(size_t)rest * DIM_CONV + c];
    bf16* p = cs + ((size_t)(b * L_SEQ + chunk * 64)) * CS_LD + c;
    for (int i = 0; i < 64; i++) {
        run += bf2f(p[0]);
        p[0] = __float2bfloat16(run);
        p += CS_LD;
    }
}

// ---------------------------------------------------------------------------
// match + gated RMSNorm. One block per (b,l). Writes out_n IN-PLACE into the
// cs row (cols [0,1536), row stride CS_LD).
// ---------------------------------------------------------------------------
__global__ __launch_bounds__(256) void match_norm_kernel(
    bf16* __restrict__ cs, const bf16* __restrict__ qbuf,
    const bf16* __restrict__ gate, const float* __restrict__ wtab,
    const float* __restrict__ gnw)
{
    const int bl = blockIdx.x;
    bf16* csr = cs + (size_t)bl * CS_LD;
    const bf16* qr = qbuf + (size_t)bl * 768;
    const bf16* gr = gate + (size_t)bl * OUT_CPLX;
    __shared__ float inv_den[NK];
    __shared__ float wsum[4];

    if (threadIdx.x < NK)
        inv_den[threadIdx.x] = 1.0f / fmaxf(bf2f(csr[threadIdx.x]), 1e-4f);
    __syncthreads();

    float vals[6];
    float ss = 0.0f;
#pragma unroll
    for (int it = 0; it < 6; it++) {
        int c = threadIdx.x + it * 256;      // 0..1535
        int k = c >> 7;
        int r = c & 127;
        int h = r & 63;
        bool is_im = (r >= 64);
        int kq = k >> 1;
        float idn = inv_den[k];
        float sre = bf2f(csr[12 + k * 64 + h]) * idn;
        float sim = bf2f(csr[780 + k * 64 + h]) * idn;
        float qre = bf2f(qr[kq * 128 + 2 * h]);
        float qim = bf2f(qr[kq * 128 + 2 * h + 1]);
        float w = wtab[k * 64 + h];
        float m = is_im ? (sim * qre - sre * qim) : (sre * qre + sim * qim);
        m *= 0.125f * w;
        float hv = m * fsilu(bf2f(gr[c]));
        vals[it] = hv;
        ss += hv * hv;
    }
    const int lane = threadIdx.x & 63;
    const int wave = threadIdx.x >> 6;
#pragma unroll
    for (int off = 32; off > 0; off >>= 1) ss += __shfl_down(ss, off);
    if (lane == 0) wsum[wave] = ss;
    __syncthreads();
    float total = wsum[0] + wsum[1] + wsum[2] + wsum[3];
    float inv_rms = rsqrtf(total * (1.0f / (float)OUT_CPLX) + 1e-6f);
#pragma unroll
    for (int it = 0; it < 6; it++) {
        int c = threadIdx.x + it * 256;
        csr[c] = __float2bfloat16(vals[it] * inv_rms * gnw[c]);
    }
}

__global__ void sentinel_kernel(float* out, float v)
{
    if (threadIdx.x == 0) out[0] = v;
}

// ---------------------------------------------------------------------------
// Workspace layout (bytes)
// ---------------------------------------------------------------------------
#define XB_OFF 0UL                 // 16384x768 bf16       25,165,824
#define WT_IN_OFF 25165824UL       // 1664x768 bf16         2,555,904
#define WT_GATE_OFF 27721728UL     // 1536x768 bf16         2,359,296
#define WT_OUT_OFF 30081024UL      // 768x2304 bf16         3,538,944
#define WT_RO_OFF 33619968UL       // 12x384x128 bf16       1,179,648
#define SUMS_OFF 34799616UL        // 4x64x1548 fp32        1,585,152
#define PW_OFF 36384768UL          // 16384x12 fp32           786,432
#define WTAB_OFF 37171200UL        // 768 fp32                  3,072
#define CS_OFF 37174272UL          // 16384x1552 bf16      50,855,936
#define A_OFF 88030208UL           // z0 (16384x1552 bf16); later gate; later y (75,497,472)
#define QBUF_OFF 138886144UL       // 16384x768 bf16       25,165,824 (later overlapped by y tail)
#define WS_NEEDED 164051968UL      // proven available >= 166,932,480 in round 2

static inline int cdiv(long n) { return (int)((n + 255) / 256); }

extern "C" void kernel_launch(void* const* d_in, const int* in_sizes, int n_in,
                              void* d_out, int out_size, void* d_ws, size_t ws_size,
                              hipStream_t stream)
{
    const float* x = (const float*)d_in[0];
    const float* W_in = (const float*)d_in[1];
    const float* conv_w = (const float*)d_in[2];
    const float* theta_raw = (const float*)d_in[3];
    const float* w_int_raw = (const float*)d_in[4];
    const float* decay_slopes = (const float*)d_in[5];
    const float* score_scale = (const float*)d_in[6];
    const float* score_bias = (const float*)d_in[7];
    const float* phase_scale = (const float*)d_in[8];
    const float* gnw = (const float*)d_in[9];
    const float* W_readout = (const float*)d_in[10];
    const float* W_gate = (const float*)d_in[11];
    const float* W_out = (const float*)d_in[12];

    if (ws_size < WS_NEEDED) {
        sentinel_kernel<<<1, 64, 0, stream>>>((float*)d_out, (float)ws_size);
        return;
    }

    char* ws = (char*)d_ws;
    bf16* xb = (bf16*)(ws + XB_OFF);
    bf16* WT_IN = (bf16*)(ws + WT_IN_OFF);
    bf16* WT_GATE = (bf16*)(ws + WT_GATE_OFF);
    bf16* WT_OUT = (bf16*)(ws + WT_OUT_OFF);
    bf16* WT_RO = (bf16*)(ws + WT_RO_OFF);
    float* sums = (float*)(ws + SUMS_OFF);
    float* pw_buf = (float*)(ws + PW_OFF);
    float* wtab = (float*)(ws + WTAB_OFF);
    bf16* cs = (bf16*)(ws + CS_OFF);
    bf16* z0 = (bf16*)(ws + A_OFF);           // 16384x1552
    bf16* gate = (bf16*)(ws + A_OFF);         // 16384x1536 (after z0 dead)
    bf16* y = (bf16*)(ws + A_OFF);            // 16384x2304 (after gate+qbuf dead)
    bf16* qbuf = (bf16*)(ws + QBUF_OFF);      // 16384x768

    // 0. convert x to bf16; weight prep
    convert_f2b<<<cdiv(16384L * 768 / 4), 256, 0, stream>>>(x, xb, 16384L * 768);
    transpose_pad_f2b<<<cdiv(1664L * 768), 256, 0, stream>>>(W_in, WT_IN, 768, 1548, 1664);
    transpose_pad_f2b<<<cdiv(1536L * 768), 256, 0, stream>>>(W_gate, WT_GATE, 768, 1536, 1536);
    transpose_pad_f2b<<<cdiv(768L * 2304), 256, 0, stream>>>(W_out, WT_OUT, 2304, 768, 768);
    transpose_ro_f2b<<<cdiv(12L * 384 * 128), 256, 0, stream>>>(W_readout, WT_RO);
    prep_wint<<<3, 256, 0, stream>>>(w_int_raw, wtab);

    // 1. z0 = x @ W_in (bf16 out, ldc 1552, cols clipped at 1548)
    gemm_kernel<true><<<dim3(128, 13), 256, 0, stream>>>(xb, 768, WT_IN, 768, z0, Z_LD, 768, 1548);

    // 2. p_w table (computed once)
    pw_kernel<<<12, 256, 0, stream>>>(z0, conv_w, decay_slopes, score_scale, score_bias, pw_buf);

    // 3. terms -> cs/qbuf + chunk sums; chunk scan; in-place cumsum
    scan_terms<<<1548, 256, 0, stream>>>(z0, conv_w, theta_raw, phase_scale, pw_buf,
                                         cs, qbuf, sums);
    scan_mid<<<cdiv((long)B_SZ * DIM_CONV), 256, 0, stream>>>(sums);
    scan_inplace<<<1548, 256, 0, stream>>>(cs, sums);

    // 4. gate = x @ W_gate (bf16, overwrites z0 region)
    gemm_kernel<true><<<dim3(128, 12), 256, 0, stream>>>(xb, 768, WT_GATE, 768, gate, 1536, 768, 1536);

    // 5. match + gated rmsnorm -> out_n in-place into cs rows
    match_norm_kernel<<<NROW, 256, 0, stream>>>(cs, qbuf, gate, wtab, gnw);

    // 6. readout GEMM + fused GLU -> y (bf16)
    gemm_readout_glu<<<dim3(128, 3, 12), 256, 0, stream>>>(
        cs, CS_LD, 128L, WT_RO, 128, 49152L, y, 128);

    // 7. out = y @ W_out (fp32 out)
    gemm_kernel<false><<<dim3(128, 6), 256, 0, stream>>>(y, 2304, WT_OUT, 2304,
                                                         (float*)d_out, 768, 2304, 768);
}

// Round 5
// 470.141 us; speedup vs baseline: 1.9628x; 1.0539x over previous
//
#include <hip/hip_runtime.h>
#include <hip/hip_bf16.h>

typedef __hip_bfloat16 bf16;
typedef __attribute__((ext_vector_type(8))) short short8;
typedef __attribute__((ext_vector_type(4))) float floatx4;

#define L_SEQ 4096
#define B_SZ 4
#define NROW 16384          // B*L
#define NK 12
#define DIM_CONV 1548
#define Z_LD 1552           // z0 row stride: cols [0,768)=kv, [768,1536)=q, [1536,1548)=s
#define OUT_CPLX 1536
#define CS_LD 1552          // cs row stride: [0,768)=re, [768,1536)=im, [1536,1548)=pw
#define NCHUNK 128
#define CLEN 32

__device__ __forceinline__ float bf2f(bf16 v) { return __bfloat162float(v); }
__device__ __forceinline__ float s2f(short v) {
    unsigned u = ((unsigned)(unsigned short)v) << 16;
    return __builtin_bit_cast(float, u);
}
__device__ __forceinline__ short f2s(float x) {
    bf16 b = __float2bfloat16(x);
    return __builtin_bit_cast(short, b);
}
__device__ __forceinline__ float frcp(float x) { return __builtin_amdgcn_rcpf(x); }
__device__ __forceinline__ float fsigmoid(float x) { return frcp(1.0f + __expf(-x)); }
__device__ __forceinline__ float fsilu(float x) { return x * fsigmoid(x); }
__device__ __forceinline__ float fsoftplus(float x) {
    return fmaxf(x, 0.0f) + __logf(1.0f + __expf(-fabsf(x)));
}

// ---------------------------------------------------------------------------
// bf16 MFMA GEMM v2 (unchanged from round 4): 128x128 tile, BK=64, XOR-swizzle.
// ---------------------------------------------------------------------------
#define GEMM_CORE2(A_, lda_, Bt_, ldb_, Kd_)                                             \
    __shared__ __align__(16) short lds_a[128 * 64];                                      \
    __shared__ __align__(16) short lds_b[128 * 64];                                      \
    const int tid = threadIdx.x;                                                         \
    const int wave = tid >> 6;                                                           \
    const int lane = tid & 63;                                                           \
    const bf16* ga[4];                                                                   \
    const bf16* gb[4];                                                                   \
    short* la[4];                                                                        \
    short* lb[4];                                                                        \
    _Pragma("unroll") for (int s = 0; s < 4; s++) {                                      \
        int p = s * 256 + wave * 64 + lane;                                              \
        int row = p >> 3;                                                                \
        int k8 = (p & 7) ^ (row & 7);                                                    \
        ga[s] = A_ + (size_t)row * lda_ + k8 * 8;                                        \
        gb[s] = Bt_ + (size_t)row * ldb_ + k8 * 8;                                       \
        la[s] = lds_a + (size_t)(s * 256 + wave * 64) * 8;                               \
        lb[s] = lds_b + (size_t)(s * 256 + wave * 64) * 8;                               \
    }                                                                                    \
    floatx4 acc[4][4];                                                                   \
    _Pragma("unroll") for (int i = 0; i < 4; i++)                                        \
        _Pragma("unroll") for (int j = 0; j < 4; j++)                                    \
            acc[i][j] = (floatx4){0.f, 0.f, 0.f, 0.f};                                   \
    const int wm = (wave >> 1) * 64;                                                     \
    const int wn = (wave & 1) * 64;                                                      \
    const int lrow = lane & 15;                                                          \
    const int lk8 = lane >> 4;                                                           \
    for (int k0 = 0; k0 < Kd_; k0 += 64) {                                               \
        _Pragma("unroll") for (int s = 0; s < 4; s++) {                                  \
            __builtin_amdgcn_global_load_lds((const __attribute__((address_space(1))) void*)ga[s], \
                                             (__attribute__((address_space(3))) void*)la[s], 16, 0, 0); \
            __builtin_amdgcn_global_load_lds((const __attribute__((address_space(1))) void*)gb[s], \
                                             (__attribute__((address_space(3))) void*)lb[s], 16, 0, 0); \
            ga[s] += 64; gb[s] += 64;                                                    \
        }                                                                                \
        __syncthreads();                                                                 \
        _Pragma("unroll") for (int s2 = 0; s2 < 2; s2++) {                               \
            short8 af[4], bfv[4];                                                        \
            const int k8L = s2 * 4 + lk8;                                                \
            _Pragma("unroll") for (int i = 0; i < 4; i++) {                              \
                int m = wm + i * 16 + lrow;                                              \
                af[i] = *(const short8*)(lds_a + ((size_t)m * 8 + (k8L ^ (m & 7))) * 8); \
            }                                                                            \
            _Pragma("unroll") for (int j = 0; j < 4; j++) {                              \
                int n = wn + j * 16 + lrow;                                              \
                bfv[j] = *(const short8*)(lds_b + ((size_t)n * 8 + (k8L ^ (n & 7))) * 8); \
            }                                                                            \
            _Pragma("unroll") for (int i = 0; i < 4; i++)                                \
                _Pragma("unroll") for (int j = 0; j < 4; j++)                            \
                    acc[i][j] = __builtin_amdgcn_mfma_f32_16x16x32_bf16(af[i], bfv[j], acc[i][j], 0, 0, 0); \
        }                                                                                \
        __syncthreads();                                                                 \
    }

template <bool OUT_BF16>
__global__ __launch_bounds__(256, 2) void gemm_kernel(
    const bf16* __restrict__ A, int lda,
    const bf16* __restrict__ Bt, int ldb,
    void* __restrict__ Cv, int ldc, int Kd, int nmax)
{
    const bf16* Ab = A + (size_t)blockIdx.x * 128 * lda;
    const bf16* Bb = Bt + (size_t)blockIdx.y * 128 * ldb;
    GEMM_CORE2(Ab, lda, Bb, ldb, Kd)
    const int orow = blockIdx.x * 128 + wm + (lk8 << 2);
    const int ocol = blockIdx.y * 128 + wn + lrow;
    if (OUT_BF16) {
        bf16* C = (bf16*)Cv;
#pragma unroll
        for (int i = 0; i < 4; i++)
#pragma unroll
            for (int j = 0; j < 4; j++)
                if (ocol + j * 16 < nmax)
#pragma unroll
                    for (int r = 0; r < 4; r++)
                        C[(size_t)(orow + i * 16 + r) * ldc + (ocol + j * 16)] =
                            __float2bfloat16(acc[i][j][r]);
    } else {
        float* C = (float*)Cv;
#pragma unroll
        for (int i = 0; i < 4; i++)
#pragma unroll
            for (int j = 0; j < 4; j++)
                if (ocol + j * 16 < nmax)
#pragma unroll
                    for (int r = 0; r < 4; r++)
                        C[(size_t)(orow + i * 16 + r) * ldc + (ocol + j * 16)] = acc[i][j][r];
    }
}

// Readout GEMM with fused GLU epilogue (pair-interleaved Bt cols).
__global__ __launch_bounds__(256, 2) void gemm_readout_glu(
    const bf16* __restrict__ A, int lda, long a_zoff,
    const bf16* __restrict__ Bt, int ldb, long b_zoff,
    bf16* __restrict__ Y, int Kd)
{
    const int z = blockIdx.z;
    const bf16* Ab = A + (long)z * a_zoff + (size_t)blockIdx.x * 128 * lda;
    const bf16* Bb = Bt + (long)z * b_zoff + (size_t)blockIdx.y * 128 * ldb;
    GEMM_CORE2(Ab, lda, Bb, ldb, Kd)
    const int orow = blockIdx.x * 128 + wm + (lk8 << 2);
    const int pcol0 = blockIdx.y * 128 + wn + lrow;
    const bool is_v = ((lane & 1) == 0);
    bf16* Yk = Y + (long)z * 192;
#pragma unroll
    for (int i = 0; i < 4; i++)
#pragma unroll
        for (int j = 0; j < 4; j++)
#pragma unroll
            for (int r = 0; r < 4; r++) {
                float v = acc[i][j][r];
                float g = __shfl_xor(v, 1);
                float o = v * fsigmoid(g);
                if (is_v)
                    Yk[(size_t)(orow + i * 16 + r) * 2304 + ((pcol0 + j * 16) >> 1)] =
                        __float2bfloat16(o);
            }
}

// ---------------------------------------------------------------------------
// convert x -> bf16, 8 elems/thread (16B load x2, 16B store)
// ---------------------------------------------------------------------------
__global__ void convert_f2b8(const float* __restrict__ in, bf16* __restrict__ out, long n)
{
    long gid = ((long)blockIdx.x * 256 + threadIdx.x) * 8;
    if (gid >= n) return;
    float4 a = *(const float4*)(in + gid);
    float4 b = *(const float4*)(in + gid + 4);
    short8 o;
    o[0] = f2s(a.x); o[1] = f2s(a.y); o[2] = f2s(a.z); o[3] = f2s(a.w);
    o[4] = f2s(b.x); o[5] = f2s(b.y); o[6] = f2s(b.z); o[7] = f2s(b.w);
    *(short8*)(out + gid) = o;
}

// ---------------------------------------------------------------------------
// Tiled transpose fp32->bf16: out[(c*mul+add)*ld_out + r] = in[r*ld_in + c]
// ---------------------------------------------------------------------------
__global__ __launch_bounds__(256) void transpose_tiled(
    const float* __restrict__ in, long in_base, int ld_in, long zo_in,
    bf16* __restrict__ out, long out_base, int ld_out, long zo_out,
    int R, int C, int mul, int add)
{
    __shared__ float t[32][33];
    const int z = blockIdx.z;
    in += in_base + (long)z * zo_in;
    out += out_base + (long)z * zo_out;
    int c0 = blockIdx.x * 32, r0 = blockIdx.y * 32;
    int tx = threadIdx.x & 31, ty = threadIdx.x >> 5;   // 32x8
#pragma unroll
    for (int i = 0; i < 32; i += 8) {
        int r = r0 + ty + i, c = c0 + tx;
        if (r < R && c < C) t[ty + i][tx] = in[(size_t)r * ld_in + c];
    }
    __syncthreads();
#pragma unroll
    for (int i = 0; i < 32; i += 8) {
        int c = c0 + ty + i, r = r0 + tx;
        if (c < C && r < R)
            out[(size_t)(c * mul + add) * ld_out + r] = __float2bfloat16(t[tx][ty + i]);
    }
}

// w_int table: wtab[i] = e^w / (e^w + 1e-6)
__global__ void prep_wint(const float* __restrict__ w_raw, float* __restrict__ wtab)
{
    int i = blockIdx.x * 256 + threadIdx.x;
    if (i >= 768) return;
    float e = __expf(w_raw[i]);
    wtab[i] = e * frcp(e + 1e-6f);
}

// ---------------------------------------------------------------------------
// pw_kernel: p_w[b][l][k] computed once. Thread = (b, chunk, k), CLEN=32.
// ---------------------------------------------------------------------------
__global__ __launch_bounds__(256) void pw_kernel(
    const bf16* __restrict__ z0, const float* __restrict__ conv_w,
    const float* __restrict__ decay, const float* __restrict__ sscale,
    const float* __restrict__ sbias, float* __restrict__ pw_buf)
{
    int gid = blockIdx.x * 256 + threadIdx.x;
    if (gid >= B_SZ * NCHUNK * NK) return;
    int k = gid % NK;
    int rest = gid / NK;
    int chunk = rest & (NCHUNK - 1);
    int b = rest >> 7;
    int l0 = chunk * CLEN;
    const int zc = 1536 + k;               // s channel in new z0 layout
    const int wc = 768 + k;                // s channel in conv_w (original order)
    const bf16* zb = z0 + (size_t)b * L_SEQ * Z_LD;
    float w0 = conv_w[0 * DIM_CONV + wc], w1 = conv_w[1 * DIM_CONV + wc];
    float w2 = conv_w[2 * DIM_CONV + wc], w3 = conv_w[3 * DIM_CONV + wc];
    float ss = sscale[k], sb = sbias[k];
    float slope = fsoftplus(decay[k]);
    float h1 = (l0 >= 3) ? bf2f(zb[(size_t)(l0 - 3) * Z_LD + zc]) : 0.f;
    float h2 = (l0 >= 2) ? bf2f(zb[(size_t)(l0 - 2) * Z_LD + zc]) : 0.f;
    float h3 = (l0 >= 1) ? bf2f(zb[(size_t)(l0 - 1) * Z_LD + zc]) : 0.f;
    for (int i = 0; i < CLEN; i++) {
        int l = l0 + i;
        float cur = bf2f(zb[(size_t)l * Z_LD + zc]);
        float s = fsilu(w0 * h1 + w1 * h2 + w2 * h3 + w3 * cur);
        h1 = h2; h2 = h3; h3 = cur;
        float pw = fsoftplus(ss * s + sb) * __expf(-slope * (float)(L_SEQ - 1 - l));
        pw = fminf(fmaxf(pw, 1e-4f), 5000.0f);
        pw_buf[((size_t)(b * L_SEQ + l)) * NK + k] = pw;
    }
}

// ---------------------------------------------------------------------------
// scan_terms: one block per rest=(b,chunk); thread tau handles 8 cols.
//   tau in [0,96): kv -> re/im terms (cs cols cv0, 768+cv0) + sums
//   tau in [96,192): q -> qbuf
//   tau 192/193: pw terms -> cs cols 1536+; pads 1548..1551 zeroed
// ---------------------------------------------------------------------------
__global__ __launch_bounds__(256) void scan_terms(
    const bf16* __restrict__ z0, const float* __restrict__ conv_w,
    const float* __restrict__ theta_raw, const float* __restrict__ pscale,
    const float* __restrict__ pw_buf,
    bf16* __restrict__ cs, bf16* __restrict__ qbuf, float* __restrict__ sums)
{
    const int rest = blockIdx.x;              // b*128 + chunk
    const int chunk = rest & (NCHUNK - 1);
    const int b = rest >> 7;
    const int l0 = chunk * CLEN;
    const int tau = threadIdx.x;
    if (tau >= 194) return;
    const bf16* zb = z0 + (size_t)b * L_SEQ * Z_LD;
    bf16* csb = cs + (size_t)b * L_SEQ * CS_LD;
    const size_t bL = (size_t)b * L_SEQ;
    float* srow = sums + (size_t)rest * 1552;

    if (tau < 96) {
        const int cv0 = tau * 8;
        const int k = cv0 >> 6;
        float wt[4][8], th[8];
#pragma unroll
        for (int t = 0; t < 4; t++)
#pragma unroll
            for (int j = 0; j < 8; j++) wt[t][j] = conv_w[t * DIM_CONV + cv0 + j];
#pragma unroll
        for (int j = 0; j < 8; j++)
            th[j] = 0.001f + 2.999f * fsigmoid(theta_raw[cv0 + j]);
        const float ps = pscale[k];
        float h1[8], h2[8], h3[8];
#pragma unroll
        for (int j = 0; j < 8; j++) { h1[j] = 0.f; h2[j] = 0.f; h3[j] = 0.f; }
        if (l0 >= 1) {
            short8 v = *(const short8*)(zb + (size_t)(l0 - 1) * Z_LD + cv0);
#pragma unroll
            for (int j = 0; j < 8; j++) h3[j] = s2f(v[j]);
            short8 u = *(const short8*)(zb + (size_t)(l0 - 2) * Z_LD + cv0);
#pragma unroll
            for (int j = 0; j < 8; j++) h2[j] = s2f(u[j]);
            short8 w = *(const short8*)(zb + (size_t)(l0 - 3) * Z_LD + cv0);
#pragma unroll
            for (int j = 0; j < 8; j++) h1[j] = s2f(w[j]);
        }
        float sre[8], sim[8];
#pragma unroll
        for (int j = 0; j < 8; j++) { sre[j] = 0.f; sim[j] = 0.f; }
        for (int i = 0; i < CLEN; i++) {
            int l = l0 + i;
            short8 zv = *(const short8*)(zb + (size_t)l * Z_LD + cv0);
            float pw = pw_buf[(bL + l) * NK + k];
            short8 vr, vi;
#pragma unroll
            for (int j = 0; j < 8; j++) {
                float cur = s2f(zv[j]);
                float kv = fsilu(wt[0][j] * h1[j] + wt[1][j] * h2[j] + wt[2][j] * h3[j] + wt[3][j] * cur);
                h1[j] = h2[j]; h2[j] = h3[j]; h3[j] = cur;
                float ksv = kv * ps;
                float phi = ksv * frcp(1.0f + fabsf(ksv)) * th[j];
                float sn = __sinf(phi);
                float cn = __cosf(phi);
                float kvw = kv * pw;
                short tr = f2s(kvw * cn);
                short ti = f2s(kvw * sn);
                vr[j] = tr; vi[j] = ti;
                sre[j] += s2f(tr);
                sim[j] += s2f(ti);
            }
            *(short8*)(csb + (size_t)l * CS_LD + cv0) = vr;
            *(short8*)(csb + (size_t)l * CS_LD + 768 + cv0) = vi;
        }
#pragma unroll
        for (int j = 0; j < 8; j++) {
            srow[cv0 + j] = sre[j];
            srow[768 + cv0 + j] = sim[j];
        }
    } else if (tau < 192) {
        const int qc0 = (tau - 96) * 8;
        const int zc0 = 768 + qc0;           // q channels in new z0 layout
        const int wc0 = 780 + qc0;           // q channels in conv_w (original)
        float wt[4][8];
#pragma unroll
        for (int t = 0; t < 4; t++)
#pragma unroll
            for (int j = 0; j < 8; j++) wt[t][j] = conv_w[t * DIM_CONV + wc0 + j];
        float h1[8], h2[8], h3[8];
#pragma unroll
        for (int j = 0; j < 8; j++) { h1[j] = 0.f; h2[j] = 0.f; h3[j] = 0.f; }
        if (l0 >= 1) {
            short8 v = *(const short8*)(zb + (size_t)(l0 - 1) * Z_LD + zc0);
#pragma unroll
            for (int j = 0; j < 8; j++) h3[j] = s2f(v[j]);
            short8 u = *(const short8*)(zb + (size_t)(l0 - 2) * Z_LD + zc0);
#pragma unroll
            for (int j = 0; j < 8; j++) h2[j] = s2f(u[j]);
            short8 w = *(const short8*)(zb + (size_t)(l0 - 3) * Z_LD + zc0);
#pragma unroll
            for (int j = 0; j < 8; j++) h1[j] = s2f(w[j]);
        }
        for (int i = 0; i < CLEN; i++) {
            int l = l0 + i;
            short8 zv = *(const short8*)(zb + (size_t)l * Z_LD + zc0);
            short8 o;
#pragma unroll
            for (int j = 0; j < 8; j++) {
                float cur = s2f(zv[j]);
                float q = fsilu(wt[0][j] * h1[j] + wt[1][j] * h2[j] + wt[2][j] * h3[j] + wt[3][j] * cur);
                h1[j] = h2[j]; h2[j] = h3[j]; h3[j] = cur;
                o[j] = f2s(q);
            }
            *(short8*)(qbuf + (bL + l) * 768 + qc0) = o;
        }
    } else {
        const int k0 = (tau == 192) ? 0 : 8;
        const int nv = (tau == 192) ? 8 : 4;
        float spw[8];
#pragma unroll
        for (int j = 0; j < 8; j++) spw[j] = 0.f;
        for (int i = 0; i < CLEN; i++) {
            int l = l0 + i;
            const float* pr = pw_buf + (bL + l) * NK + k0;
            short8 o;
#pragma unroll
            for (int j = 0; j < 8; j++) {
                float v = (j < nv) ? pr[j] : 0.0f;
                short t = f2s(v);
                o[j] = t;
                spw[j] += s2f(t);
            }
            *(short8*)(csb + (size_t)l * CS_LD + 1536 + k0) = o;
        }
#pragma unroll
        for (int j = 0; j < 8; j++) srow[1536 + k0 + j] = spw[j];
    }
}

// exclusive scan of chunk sums over NCHUNK chunks, per (b, col)
__global__ void scan_mid(float* __restrict__ sums)
{
    int gid = blockIdx.x * 256 + threadIdx.x;
    if (gid >= B_SZ * 1552) return;
    int c = gid % 1552;
    int b = gid / 1552;
    float run = 0.f;
    for (int i = 0; i < NCHUNK; i++) {
        size_t idx = ((size_t)(b * NCHUNK + i)) * 1552 + c;
        float v = sums[idx];
        sums[idx] = run;
        run += v;
    }
}

// in-place cumsum over bf16 terms, 8 cols/thread, 16B loads/stores
__global__ __launch_bounds__(256) void scan_inplace(
    bf16* __restrict__ cs, const float* __restrict__ sums)
{
    const int rest = blockIdx.x;
    const int chunk = rest & (NCHUNK - 1);
    const int b = rest >> 7;
    const int tau = threadIdx.x;
    if (tau >= 194) return;
    const int c0 = tau * 8;
    float run[8];
    const float* srow = sums + (size_t)rest * 1552;
#pragma unroll
    for (int j = 0; j < 8; j++) run[j] = srow[c0 + j];
    bf16* p = cs + ((size_t)(b * L_SEQ + chunk * CLEN)) * CS_LD + c0;
    for (int i = 0; i < CLEN; i++) {
        short8 v = *(const short8*)p;
        short8 o;
#pragma unroll
        for (int j = 0; j < 8; j++) {
            run[j] += s2f(v[j]);
            o[j] = f2s(run[j]);
        }
        *(short8*)p = o;
        p += CS_LD;
    }
}

// ---------------------------------------------------------------------------
// match + gated RMSNorm, vectorized: block=192 threads, 8 cols/thread.
// Writes out_n in-place into cs cols [0,1536).
// ---------------------------------------------------------------------------
__global__ __launch_bounds__(192) void match_norm_kernel(
    bf16* __restrict__ cs, const bf16* __restrict__ qbuf,
    const bf16* __restrict__ gate, const float* __restrict__ wtab,
    const float* __restrict__ gnw)
{
    const int bl = blockIdx.x;
    bf16* csr = cs + (size_t)bl * CS_LD;
    const bf16* qr = qbuf + (size_t)bl * 768;
    const bf16* gr = gate + (size_t)bl * OUT_CPLX;
    __shared__ float inv_den[NK];
    __shared__ float wsum[3];

    if (threadIdx.x < NK)
        inv_den[threadIdx.x] = 1.0f / fmaxf(bf2f(csr[1536 + threadIdx.x]), 1e-4f);
    __syncthreads();

    const int c0 = threadIdx.x * 8;
    const int k = c0 >> 7;
    const int r0 = c0 & 127;
    const int h0 = r0 & 63;
    const bool is_im = (r0 >= 64);
    const int kq = k >> 1;
    const float idn = inv_den[k];

    short8 re8 = *(const short8*)(csr + k * 64 + h0);
    short8 im8 = *(const short8*)(csr + 768 + k * 64 + h0);
    short8 qa = *(const short8*)(qr + kq * 128 + 2 * h0);
    short8 qb = *(const short8*)(qr + kq * 128 + 2 * h0 + 8);
    short8 g8 = *(const short8*)(gr + c0);
    float4 wa = *(const float4*)(wtab + k * 64 + h0);
    float4 wb = *(const float4*)(wtab + k * 64 + h0 + 4);
    float4 na = *(const float4*)(gnw + c0);
    float4 nb = *(const float4*)(gnw + c0 + 4);
    const float* wv = (const float*)&wa;  // wa,wb contiguous? use per-element below
    (void)wv;
    float wreg[8] = {wa.x, wa.y, wa.z, wa.w, wb.x, wb.y, wb.z, wb.w};
    float nreg[8] = {na.x, na.y, na.z, na.w, nb.x, nb.y, nb.z, nb.w};

    float vals[8];
    float ss = 0.0f;
#pragma unroll
    for (int j = 0; j < 8; j++) {
        float sre = s2f(re8[j]) * idn;
        float sim = s2f(im8[j]) * idn;
        short qre_s = (j < 4) ? qa[2 * j] : qb[2 * (j - 4)];
        short qim_s = (j < 4) ? qa[2 * j + 1] : qb[2 * (j - 4) + 1];
        float qre = s2f(qre_s);
        float qim = s2f(qim_s);
        float m = is_im ? (sim * qre - sre * qim) : (sre * qre + sim * qim);
        m *= 0.125f * wreg[j];
        float hv = m * fsilu(s2f(g8[j]));
        vals[j] = hv;
        ss += hv * hv;
    }
    const int lane = threadIdx.x & 63;
    const int wv_id = threadIdx.x >> 6;
#pragma unroll
    for (int off = 32; off > 0; off >>= 1) ss += __shfl_down(ss, off);
    if (lane == 0) wsum[wv_id] = ss;
    __syncthreads();
    float total = wsum[0] + wsum[1] + wsum[2];
    float inv_rms = rsqrtf(total * (1.0f / (float)OUT_CPLX) + 1e-6f);
    short8 o;
#pragma unroll
    for (int j = 0; j < 8; j++) o[j] = f2s(vals[j] * inv_rms * nreg[j]);
    *(short8*)(csr + c0) = o;
}

__global__ void sentinel_kernel(float* out, float v)
{
    if (threadIdx.x == 0) out[0] = v;
}

// ---------------------------------------------------------------------------
// Workspace layout (bytes)
// ---------------------------------------------------------------------------
#define XB_OFF 0UL                 // 16384x768 bf16      25,165,824
#define WT_IN_OFF 25165824UL       // 1664x768 bf16        2,555,904
#define WT_GATE_OFF 27721728UL     // 1536x768 bf16        2,359,296
#define WT_OUT_OFF 30081024UL      // 768x2304 bf16        3,538,944
#define WT_RO_OFF 33619968UL       // 12x384x128 bf16      1,179,648
#define SUMS_OFF 34799616UL        // 512x1552 fp32        3,178,496
#define PW_OFF 37978112UL          // 16384x12 fp32          786,432
#define WTAB_OFF 38764544UL        // 768 fp32                 3,072 (pad to 3072)
#define CS_OFF 38767616UL          // 16384x1552 bf16     50,855,936
#define A_OFF 89623552UL           // z0 16384x1552 bf16; later gate; later y (75,497,472)
#define QBUF_OFF 140479488UL       // 16384x768 bf16      25,165,824 (overlapped by y tail later)
#define WS_NEEDED 165645312UL      // < 166,932,480 proven available (round 2)

static inline int cdiv(long n) { return (int)((n + 255) / 256); }

extern "C" void kernel_launch(void* const* d_in, const int* in_sizes, int n_in,
                              void* d_out, int out_size, void* d_ws, size_t ws_size,
                              hipStream_t stream)
{
    const float* x = (const float*)d_in[0];
    const float* W_in = (const float*)d_in[1];
    const float* conv_w = (const float*)d_in[2];
    const float* theta_raw = (const float*)d_in[3];
    const float* w_int_raw = (const float*)d_in[4];
    const float* decay_slopes = (const float*)d_in[5];
    const float* score_scale = (const float*)d_in[6];
    const float* score_bias = (const float*)d_in[7];
    const float* phase_scale = (const float*)d_in[8];
    const float* gnw = (const float*)d_in[9];
    const float* W_readout = (const float*)d_in[10];
    const float* W_gate = (const float*)d_in[11];
    const float* W_out = (const float*)d_in[12];

    if (ws_size < WS_NEEDED) {
        sentinel_kernel<<<1, 64, 0, stream>>>((float*)d_out, (float)ws_size);
        return;
    }

    char* ws = (char*)d_ws;
    bf16* xb = (bf16*)(ws + XB_OFF);
    bf16* WT_IN = (bf16*)(ws + WT_IN_OFF);
    bf16* WT_GATE = (bf16*)(ws + WT_GATE_OFF);
    bf16* WT_OUT = (bf16*)(ws + WT_OUT_OFF);
    bf16* WT_RO = (bf16*)(ws + WT_RO_OFF);
    float* sums = (float*)(ws + SUMS_OFF);
    float* pw_buf = (float*)(ws + PW_OFF);
    float* wtab = (float*)(ws + WTAB_OFF);
    bf16* cs = (bf16*)(ws + CS_OFF);
    bf16* z0 = (bf16*)(ws + A_OFF);
    bf16* gate = (bf16*)(ws + A_OFF);
    bf16* y = (bf16*)(ws + A_OFF);
    bf16* qbuf = (bf16*)(ws + QBUF_OFF);

    // 0. convert x; weight prep (tiled transposes; W_in column-permuted kv|q|s)
    convert_f2b8<<<6144, 256, 0, stream>>>(x, xb, 16384L * 768);
    transpose_tiled<<<dim3(24, 24), 256, 0, stream>>>(W_in, 0, 1548, 0, WT_IN, 0, 768, 0, 768, 768, 1, 0);
    transpose_tiled<<<dim3(24, 24), 256, 0, stream>>>(W_in, 780, 1548, 0, WT_IN, 768L * 768, 768, 0, 768, 768, 1, 0);
    transpose_tiled<<<dim3(1, 24), 256, 0, stream>>>(W_in, 768, 1548, 0, WT_IN, 1536L * 768, 768, 0, 768, 12, 1, 0);
    transpose_tiled<<<dim3(48, 24), 256, 0, stream>>>(W_gate, 0, 1536, 0, WT_GATE, 0, 768, 0, 768, 1536, 1, 0);
    transpose_tiled<<<dim3(24, 72), 256, 0, stream>>>(W_out, 0, 768, 0, WT_OUT, 0, 2304, 0, 2304, 768, 1, 0);
    transpose_tiled<<<dim3(6, 4, 12), 256, 0, stream>>>(W_readout, 0, 384, 49152, WT_RO, 0, 128, 49152, 128, 192, 2, 0);
    transpose_tiled<<<dim3(6, 4, 12), 256, 0, stream>>>(W_readout, 192, 384, 49152, WT_RO, 0, 128, 49152, 128, 192, 2, 1);
    prep_wint<<<3, 256, 0, stream>>>(w_int_raw, wtab);

    // 1. z0 = x @ W_in (bf16, ldc 1552, cols clipped at 1548; layout kv|q|s)
    gemm_kernel<true><<<dim3(128, 13), 256, 0, stream>>>(xb, 768, WT_IN, 768, z0, Z_LD, 768, 1548);

    // 2. p_w table
    pw_kernel<<<24, 256, 0, stream>>>(z0, conv_w, decay_slopes, score_scale, score_bias, pw_buf);

    // 3. terms + chunk sums; chunk scan; in-place cumsum
    scan_terms<<<512, 256, 0, stream>>>(z0, conv_w, theta_raw, phase_scale, pw_buf,
                                        cs, qbuf, sums);
    scan_mid<<<25, 256, 0, stream>>>(sums);
    scan_inplace<<<512, 256, 0, stream>>>(cs, sums);

    // 4. gate = x @ W_gate (overwrites z0)
    gemm_kernel<true><<<dim3(128, 12), 256, 0, stream>>>(xb, 768, WT_GATE, 768, gate, 1536, 768, 1536);

    // 5. match + gated rmsnorm -> out_n in-place into cs
    match_norm_kernel<<<NROW, 192, 0, stream>>>(cs, qbuf, gate, wtab, gnw);

    // 6. readout GEMM + fused GLU -> y
    gemm_readout_glu<<<dim3(128, 3, 12), 256, 0, stream>>>(
        cs, CS_LD, 128L, WT_RO, 128, 49152L, y, 128);

    // 7. out = y @ W_out (fp32)
    gemm_kernel<false><<<dim3(128, 6), 256, 0, stream>>>(y, 2304, WT_OUT, 2304,
                                                         (float*)d_out, 768, 2304, 768);
}

// Round 6
// 445.949 us; speedup vs baseline: 2.0693x; 1.0542x over previous
//
#include <hip/hip_runtime.h>
#include <hip/hip_bf16.h>

typedef __hip_bfloat16 bf16;
typedef __attribute__((ext_vector_type(8))) short short8;
typedef __attribute__((ext_vector_type(4))) float floatx4;

#define L_SEQ 4096
#define B_SZ 4
#define NROW 16384          // B*L
#define NK 12
#define DIM_CONV 1548
#define Z_LD 1552           // z0 row stride: [0,768)=kv, [768,1536)=q, [1536,1548)=s
#define OUT_CPLX 1536
#define CS_LD 1552          // cs row stride: [0,768)=re, [768,1536)=im, [1536,1548)=pw
#define NCHUNK 128
#define CLEN 32

__device__ __forceinline__ float bf2f(bf16 v) { return __bfloat162float(v); }
__device__ __forceinline__ float s2f(short v) {
    unsigned u = ((unsigned)(unsigned short)v) << 16;
    return __builtin_bit_cast(float, u);
}
__device__ __forceinline__ short f2s(float x) {
    bf16 b = __float2bfloat16(x);
    return __builtin_bit_cast(short, b);
}
__device__ __forceinline__ float frcp(float x) { return __builtin_amdgcn_rcpf(x); }
__device__ __forceinline__ float fsigmoid(float x) { return frcp(1.0f + __expf(-x)); }
__device__ __forceinline__ float fsilu(float x) { return x * fsigmoid(x); }
__device__ __forceinline__ float fsoftplus(float x) {
    return fmaxf(x, 0.0f) + __logf(1.0f + __expf(-fabsf(x)));
}

// ---------------------------------------------------------------------------
// GEMM core v2 (128x128 tile, 64x64 wave tile, BK=64, XOR swizzle) — used for
// W_out and readout GEMMs (N too small for wide tiles there).
// ---------------------------------------------------------------------------
#define GEMM_CORE2(A_, lda_, Bt_, ldb_, Kd_)                                             \
    __shared__ __align__(16) short lds_a[128 * 64];                                      \
    __shared__ __align__(16) short lds_b[128 * 64];                                      \
    const int tid = threadIdx.x;                                                         \
    const int wave = tid >> 6;                                                           \
    const int lane = tid & 63;                                                           \
    const bf16* ga[4];                                                                   \
    const bf16* gb[4];                                                                   \
    short* la[4];                                                                        \
    short* lb[4];                                                                        \
    _Pragma("unroll") for (int s = 0; s < 4; s++) {                                      \
        int p = s * 256 + tid;                                                           \
        int row = p >> 3;                                                                \
        int k8 = (p & 7) ^ (row & 7);                                                    \
        ga[s] = A_ + (size_t)row * lda_ + k8 * 8;                                        \
        gb[s] = Bt_ + (size_t)row * ldb_ + k8 * 8;                                       \
        la[s] = lds_a + (size_t)(s * 256 + wave * 64) * 8;                               \
        lb[s] = lds_b + (size_t)(s * 256 + wave * 64) * 8;                               \
    }                                                                                    \
    floatx4 acc[4][4];                                                                   \
    _Pragma("unroll") for (int i = 0; i < 4; i++)                                        \
        _Pragma("unroll") for (int j = 0; j < 4; j++)                                    \
            acc[i][j] = (floatx4){0.f, 0.f, 0.f, 0.f};                                   \
    const int wm = (wave >> 1) * 64;                                                     \
    const int wn = (wave & 1) * 64;                                                      \
    const int lrow = lane & 15;                                                          \
    const int lk8 = lane >> 4;                                                           \
    for (int k0 = 0; k0 < Kd_; k0 += 64) {                                               \
        _Pragma("unroll") for (int s = 0; s < 4; s++) {                                  \
            __builtin_amdgcn_global_load_lds((const __attribute__((address_space(1))) void*)ga[s], \
                                             (__attribute__((address_space(3))) void*)la[s], 16, 0, 0); \
            __builtin_amdgcn_global_load_lds((const __attribute__((address_space(1))) void*)gb[s], \
                                             (__attribute__((address_space(3))) void*)lb[s], 16, 0, 0); \
            ga[s] += 64; gb[s] += 64;                                                    \
        }                                                                                \
        __syncthreads();                                                                 \
        _Pragma("unroll") for (int s2 = 0; s2 < 2; s2++) {                               \
            short8 af[4], bfv[4];                                                        \
            const int k8L = s2 * 4 + lk8;                                                \
            _Pragma("unroll") for (int i = 0; i < 4; i++) {                              \
                int m = wm + i * 16 + lrow;                                              \
                af[i] = *(const short8*)(lds_a + ((size_t)m * 8 + (k8L ^ (m & 7))) * 8); \
            }                                                                            \
            _Pragma("unroll") for (int j = 0; j < 4; j++) {                              \
                int n = wn + j * 16 + lrow;                                              \
                bfv[j] = *(const short8*)(lds_b + ((size_t)n * 8 + (k8L ^ (n & 7))) * 8); \
            }                                                                            \
            _Pragma("unroll") for (int i = 0; i < 4; i++)                                \
                _Pragma("unroll") for (int j = 0; j < 4; j++)                            \
                    acc[i][j] = __builtin_amdgcn_mfma_f32_16x16x32_bf16(af[i], bfv[j], acc[i][j], 0, 0, 0); \
        }                                                                                \
        __syncthreads();                                                                 \
    }

template <bool OUT_BF16>
__global__ __launch_bounds__(256, 2) void gemm_kernel(
    const bf16* __restrict__ A, int lda,
    const bf16* __restrict__ Bt, int ldb,
    void* __restrict__ Cv, int ldc, int Kd, int nmax)
{
    const bf16* Ab = A + (size_t)blockIdx.x * 128 * lda;
    const bf16* Bb = Bt + (size_t)blockIdx.y * 128 * ldb;
    GEMM_CORE2(Ab, lda, Bb, ldb, Kd)
    const int orow = blockIdx.x * 128 + wm + (lk8 << 2);
    const int ocol = blockIdx.y * 128 + wn + lrow;
    if (OUT_BF16) {
        bf16* C = (bf16*)Cv;
#pragma unroll
        for (int i = 0; i < 4; i++)
#pragma unroll
            for (int j = 0; j < 4; j++)
                if (ocol + j * 16 < nmax)
#pragma unroll
                    for (int r = 0; r < 4; r++)
                        C[(size_t)(orow + i * 16 + r) * ldc + (ocol + j * 16)] =
                            __float2bfloat16(acc[i][j][r]);
    } else {
        float* C = (float*)Cv;
#pragma unroll
        for (int i = 0; i < 4; i++)
#pragma unroll
            for (int j = 0; j < 4; j++)
                if (ocol + j * 16 < nmax)
#pragma unroll
                    for (int r = 0; r < 4; r++)
                        C[(size_t)(orow + i * 16 + r) * ldc + (ocol + j * 16)] = acc[i][j][r];
    }
}

// Readout GEMM with fused GLU epilogue (pair-interleaved Bt cols).
__global__ __launch_bounds__(256, 2) void gemm_readout_glu(
    const bf16* __restrict__ A, int lda, long a_zoff,
    const bf16* __restrict__ Bt, int ldb, long b_zoff,
    bf16* __restrict__ Y, int Kd)
{
    const int z = blockIdx.z;
    const bf16* Ab = A + (long)z * a_zoff + (size_t)blockIdx.x * 128 * lda;
    const bf16* Bb = Bt + (long)z * b_zoff + (size_t)blockIdx.y * 128 * ldb;
    GEMM_CORE2(Ab, lda, Bb, ldb, Kd)
    const int orow = blockIdx.x * 128 + wm + (lk8 << 2);
    const int pcol0 = blockIdx.y * 128 + wn + lrow;
    const bool is_v = ((lane & 1) == 0);
    bf16* Yk = Y + (long)z * 192;
#pragma unroll
    for (int i = 0; i < 4; i++)
#pragma unroll
        for (int j = 0; j < 4; j++)
#pragma unroll
            for (int r = 0; r < 4; r++) {
                float v = acc[i][j][r];
                float g = __shfl_xor(v, 1);
                float o = v * fsigmoid(g);
                if (is_v)
                    Yk[(size_t)(orow + i * 16 + r) * 2304 + ((pcol0 + j * 16) >> 1)] =
                        __float2bfloat16(o);
            }
}

// ---------------------------------------------------------------------------
// GEMM wide: 128x256 block tile, 64x128 wave tile, BK=64, XOR swizzle.
// 24 ds_read_b128 per 64 MFMA per wave per K-iter (48 B/MFMA vs 64 in CORE2)
// -> MFMA pipe becomes dominant. Used for z0 and gate GEMMs (large N).
// ---------------------------------------------------------------------------
__global__ __launch_bounds__(256, 2) void gemm_wide(
    const bf16* __restrict__ A, int lda,
    const bf16* __restrict__ Bt, int ldb,
    bf16* __restrict__ C, int ldc, int Kd, int nmax)
{
    __shared__ __align__(16) short lds_a[128 * 64];
    __shared__ __align__(16) short lds_b[256 * 64];
    const int tid = threadIdx.x;
    const int wave = tid >> 6;
    const int lane = tid & 63;
    const bf16* Ab = A + (size_t)blockIdx.x * 128 * lda;
    const bf16* Bb = Bt + (size_t)blockIdx.y * 256 * ldb;
    const bf16* ga[4]; short* la[4];
    const bf16* gb[8]; short* lb[8];
#pragma unroll
    for (int s = 0; s < 4; s++) {
        int p = s * 256 + tid;
        int row = p >> 3;
        int k8 = (p & 7) ^ (row & 7);
        ga[s] = Ab + (size_t)row * lda + k8 * 8;
        la[s] = lds_a + (size_t)(s * 256 + wave * 64) * 8;
    }
#pragma unroll
    for (int s = 0; s < 8; s++) {
        int p = s * 256 + tid;
        int row = p >> 3;
        int k8 = (p & 7) ^ (row & 7);
        gb[s] = Bb + (size_t)row * ldb + k8 * 8;
        lb[s] = lds_b + (size_t)(s * 256 + wave * 64) * 8;
    }
    floatx4 acc[4][8];
#pragma unroll
    for (int i = 0; i < 4; i++)
#pragma unroll
        for (int j = 0; j < 8; j++) acc[i][j] = (floatx4){0.f, 0.f, 0.f, 0.f};
    const int wm = (wave >> 1) * 64;
    const int wn = (wave & 1) * 128;
    const int lrow = lane & 15;
    const int lk8 = lane >> 4;
    for (int k0 = 0; k0 < Kd; k0 += 64) {
#pragma unroll
        for (int s = 0; s < 4; s++) {
            __builtin_amdgcn_global_load_lds((const __attribute__((address_space(1))) void*)ga[s],
                                             (__attribute__((address_space(3))) void*)la[s], 16, 0, 0);
            ga[s] += 64;
        }
#pragma unroll
        for (int s = 0; s < 8; s++) {
            __builtin_amdgcn_global_load_lds((const __attribute__((address_space(1))) void*)gb[s],
                                             (__attribute__((address_space(3))) void*)lb[s], 16, 0, 0);
            gb[s] += 64;
        }
        __syncthreads();
#pragma unroll
        for (int s2 = 0; s2 < 2; s2++) {
            short8 af[4], bfv[8];
            const int k8L = s2 * 4 + lk8;
#pragma unroll
            for (int i = 0; i < 4; i++) {
                int m = wm + i * 16 + lrow;
                af[i] = *(const short8*)(lds_a + ((size_t)m * 8 + (k8L ^ (m & 7))) * 8);
            }
#pragma unroll
            for (int j = 0; j < 8; j++) {
                int n = wn + j * 16 + lrow;
                bfv[j] = *(const short8*)(lds_b + ((size_t)n * 8 + (k8L ^ (n & 7))) * 8);
            }
#pragma unroll
            for (int i = 0; i < 4; i++)
#pragma unroll
                for (int j = 0; j < 8; j++)
                    acc[i][j] = __builtin_amdgcn_mfma_f32_16x16x32_bf16(af[i], bfv[j], acc[i][j], 0, 0, 0);
        }
        __syncthreads();
    }
    const int orow = blockIdx.x * 128 + wm + (lk8 << 2);
    const int ocol = blockIdx.y * 256 + wn + lrow;
#pragma unroll
    for (int i = 0; i < 4; i++)
#pragma unroll
        for (int j = 0; j < 8; j++)
            if (ocol + j * 16 < nmax)
#pragma unroll
                for (int r = 0; r < 4; r++)
                    C[(size_t)(orow + i * 16 + r) * ldc + (ocol + j * 16)] =
                        __float2bfloat16(acc[i][j][r]);
}

// ---------------------------------------------------------------------------
// prep_kernel: ONE launch for x->bf16 convert, w_int table, and all 7 weight
// transposes (fp32->bf16, tiled 32x32 via LDS). blockIdx.x range-dispatched.
// ---------------------------------------------------------------------------
#define PREP_CONV_BLKS 6144
#define PREP_WINT_BLKS 3
#define PREP_T0 (PREP_CONV_BLKS + PREP_WINT_BLKS)   // 6147
#define PREP_TOTAL (PREP_T0 + 4632)                  // 10779

__global__ __launch_bounds__(256) void prep_kernel(
    const float* __restrict__ x, const float* __restrict__ w_int_raw,
    const float* __restrict__ W_in, const float* __restrict__ W_gate,
    const float* __restrict__ W_out, const float* __restrict__ W_readout,
    bf16* __restrict__ xb, float* __restrict__ wtab,
    bf16* __restrict__ WT_IN, bf16* __restrict__ WT_GATE,
    bf16* __restrict__ WT_OUT, bf16* __restrict__ WT_RO)
{
    __shared__ float tle[32][33];
    const int blk = blockIdx.x;
    const int tid = threadIdx.x;

    if (blk < PREP_CONV_BLKS) {
        long gid = ((long)blk * 256 + tid) * 8;
        float4 a = *(const float4*)(x + gid);
        float4 b = *(const float4*)(x + gid + 4);
        short8 o;
        o[0] = f2s(a.x); o[1] = f2s(a.y); o[2] = f2s(a.z); o[3] = f2s(a.w);
        o[4] = f2s(b.x); o[5] = f2s(b.y); o[6] = f2s(b.z); o[7] = f2s(b.w);
        *(short8*)(xb + gid) = o;
        return;
    }
    if (blk < PREP_T0) {
        int i = (blk - PREP_CONV_BLKS) * 256 + tid;
        if (i < 768) {
            float e = __expf(w_int_raw[i]);
            wtab[i] = e * frcp(e + 1e-6f);
        }
        return;
    }
    int t = blk - PREP_T0;
    const float* in; bf16* out;
    int ld_in, ld_out, R, C, mul, add, nx;
    if (t < 576) {                       // W_in kv cols -> WT_IN rows 0..767
        in = W_in; out = WT_IN; ld_in = 1548; ld_out = 768;
        R = 768; C = 768; mul = 1; add = 0; nx = 24;
    } else if (t < 1152) {               // W_in q cols 780.. -> rows 768..1535
        t -= 576;
        in = W_in + 780; out = WT_IN + 768L * 768; ld_in = 1548; ld_out = 768;
        R = 768; C = 768; mul = 1; add = 0; nx = 24;
    } else if (t < 1176) {               // W_in s cols 768..779 -> rows 1536..1547
        t -= 1152;
        in = W_in + 768; out = WT_IN + 1536L * 768; ld_in = 1548; ld_out = 768;
        R = 768; C = 12; mul = 1; add = 0; nx = 1;
    } else if (t < 2328) {               // W_gate
        t -= 1176;
        in = W_gate; out = WT_GATE; ld_in = 1536; ld_out = 768;
        R = 768; C = 1536; mul = 1; add = 0; nx = 48;
    } else if (t < 4056) {               // W_out
        t -= 2328;
        in = W_out; out = WT_OUT; ld_in = 768; ld_out = 2304;
        R = 2304; C = 768; mul = 1; add = 0; nx = 24;
    } else if (t < 4344) {               // W_readout val half (pair-interleave)
        t -= 4056;
        int k = t / 24; t %= 24;
        in = W_readout + (long)k * 49152; out = WT_RO + (long)k * 49152;
        ld_in = 384; ld_out = 128; R = 128; C = 192; mul = 2; add = 0; nx = 6;
    } else {                             // W_readout gate half
        t -= 4344;
        int k = t / 24; t %= 24;
        in = W_readout + (long)k * 49152 + 192; out = WT_RO + (long)k * 49152;
        ld_in = 384; ld_out = 128; R = 128; C = 192; mul = 2; add = 1; nx = 6;
    }
    int c0 = (t % nx) * 32, r0 = (t / nx) * 32;
    int tx = tid & 31, ty = tid >> 5;    // 32x8
#pragma unroll
    for (int i = 0; i < 32; i += 8) {
        int r = r0 + ty + i, c = c0 + tx;
        if (r < R && c < C) tle[ty + i][tx] = in[(size_t)r * ld_in + c];
    }
    __syncthreads();
#pragma unroll
    for (int i = 0; i < 32; i += 8) {
        int c = c0 + ty + i, r = r0 + tx;
        if (c < C && r < R)
            out[(size_t)(c * mul + add) * ld_out + r] = __float2bfloat16(tle[tx][ty + i]);
    }
}

// ---------------------------------------------------------------------------
// scan_terms (pw fused): one block per rest=(b,chunk).
// Phase 1: lanes 0..11 compute p_w for their k over CLEN positions into LDS.
// Phase 2: tau<96: kv->re/im terms; tau<192: q; tau 192/193: pw terms.
// Chunk sums accumulated from the ROUNDED bf16 terms (bit-consistent).
// ---------------------------------------------------------------------------
__global__ __launch_bounds__(256) void scan_terms(
    const bf16* __restrict__ z0, const float* __restrict__ conv_w,
    const float* __restrict__ theta_raw, const float* __restrict__ pscale,
    const float* __restrict__ decay, const float* __restrict__ sscale,
    const float* __restrict__ sbias,
    bf16* __restrict__ cs, bf16* __restrict__ qbuf, float* __restrict__ sums)
{
    __shared__ float pwl[CLEN][NK];
    const int rest = blockIdx.x;              // b*128 + chunk
    const int chunk = rest & (NCHUNK - 1);
    const int b = rest >> 7;
    const int l0 = chunk * CLEN;
    const int tau = threadIdx.x;
    const bf16* zb = z0 + (size_t)b * L_SEQ * Z_LD;
    bf16* csb = cs + (size_t)b * L_SEQ * CS_LD;
    const size_t bL = (size_t)b * L_SEQ;
    float* srow = sums + (size_t)rest * 1552;

    if (tau < NK) {
        const int k = tau;
        const int zc = 1536 + k;
        const int wc = 768 + k;
        float w0 = conv_w[0 * DIM_CONV + wc], w1 = conv_w[1 * DIM_CONV + wc];
        float w2 = conv_w[2 * DIM_CONV + wc], w3 = conv_w[3 * DIM_CONV + wc];
        float ss = sscale[k], sb = sbias[k];
        float slope = fsoftplus(decay[k]);
        float h1 = (l0 >= 3) ? bf2f(zb[(size_t)(l0 - 3) * Z_LD + zc]) : 0.f;
        float h2 = (l0 >= 2) ? bf2f(zb[(size_t)(l0 - 2) * Z_LD + zc]) : 0.f;
        float h3 = (l0 >= 1) ? bf2f(zb[(size_t)(l0 - 1) * Z_LD + zc]) : 0.f;
        for (int i = 0; i < CLEN; i++) {
            int l = l0 + i;
            float cur = bf2f(zb[(size_t)l * Z_LD + zc]);
            float s = fsilu(w0 * h1 + w1 * h2 + w2 * h3 + w3 * cur);
            h1 = h2; h2 = h3; h3 = cur;
            float pw = fsoftplus(ss * s + sb) * __expf(-slope * (float)(L_SEQ - 1 - l));
            pwl[i][k] = fminf(fmaxf(pw, 1e-4f), 5000.0f);
        }
    }
    __syncthreads();
    if (tau >= 194) return;

    if (tau < 96) {
        const int cv0 = tau * 8;
        const int k = cv0 >> 6;
        float wt[4][8], th[8];
#pragma unroll
        for (int t = 0; t < 4; t++)
#pragma unroll
            for (int j = 0; j < 8; j++) wt[t][j] = conv_w[t * DIM_CONV + cv0 + j];
#pragma unroll
        for (int j = 0; j < 8; j++)
            th[j] = 0.001f + 2.999f * fsigmoid(theta_raw[cv0 + j]);
        const float ps = pscale[k];
        float h1[8], h2[8], h3[8];
#pragma unroll
        for (int j = 0; j < 8; j++) { h1[j] = 0.f; h2[j] = 0.f; h3[j] = 0.f; }
        if (l0 >= 1) {
            short8 v = *(const short8*)(zb + (size_t)(l0 - 1) * Z_LD + cv0);
#pragma unroll
            for (int j = 0; j < 8; j++) h3[j] = s2f(v[j]);
            short8 u = *(const short8*)(zb + (size_t)(l0 - 2) * Z_LD + cv0);
#pragma unroll
            for (int j = 0; j < 8; j++) h2[j] = s2f(u[j]);
            short8 w = *(const short8*)(zb + (size_t)(l0 - 3) * Z_LD + cv0);
#pragma unroll
            for (int j = 0; j < 8; j++) h1[j] = s2f(w[j]);
        }
        float sre[8], sim[8];
#pragma unroll
        for (int j = 0; j < 8; j++) { sre[j] = 0.f; sim[j] = 0.f; }
        for (int i = 0; i < CLEN; i++) {
            int l = l0 + i;
            short8 zv = *(const short8*)(zb + (size_t)l * Z_LD + cv0);
            float pw = pwl[i][k];
            short8 vr, vi;
#pragma unroll
            for (int j = 0; j < 8; j++) {
                float cur = s2f(zv[j]);
                float kv = fsilu(wt[0][j] * h1[j] + wt[1][j] * h2[j] + wt[2][j] * h3[j] + wt[3][j] * cur);
                h1[j] = h2[j]; h2[j] = h3[j]; h3[j] = cur;
                float ksv = kv * ps;
                float phi = ksv * frcp(1.0f + fabsf(ksv)) * th[j];
                float sn = __sinf(phi);
                float cn = __cosf(phi);
                float kvw = kv * pw;
                short tr = f2s(kvw * cn);
                short ti = f2s(kvw * sn);
                vr[j] = tr; vi[j] = ti;
                sre[j] += s2f(tr);
                sim[j] += s2f(ti);
            }
            *(short8*)(csb + (size_t)l * CS_LD + cv0) = vr;
            *(short8*)(csb + (size_t)l * CS_LD + 768 + cv0) = vi;
        }
#pragma unroll
        for (int j = 0; j < 8; j++) {
            srow[cv0 + j] = sre[j];
            srow[768 + cv0 + j] = sim[j];
        }
    } else if (tau < 192) {
        const int qc0 = (tau - 96) * 8;
        const int zc0 = 768 + qc0;
        const int wc0 = 780 + qc0;
        float wt[4][8];
#pragma unroll
        for (int t = 0; t < 4; t++)
#pragma unroll
            for (int j = 0; j < 8; j++) wt[t][j] = conv_w[t * DIM_CONV + wc0 + j];
        float h1[8], h2[8], h3[8];
#pragma unroll
        for (int j = 0; j < 8; j++) { h1[j] = 0.f; h2[j] = 0.f; h3[j] = 0.f; }
        if (l0 >= 1) {
            short8 v = *(const short8*)(zb + (size_t)(l0 - 1) * Z_LD + zc0);
#pragma unroll
            for (int j = 0; j < 8; j++) h3[j] = s2f(v[j]);
            short8 u = *(const short8*)(zb + (size_t)(l0 - 2) * Z_LD + zc0);
#pragma unroll
            for (int j = 0; j < 8; j++) h2[j] = s2f(u[j]);
            short8 w = *(const short8*)(zb + (size_t)(l0 - 3) * Z_LD + zc0);
#pragma unroll
            for (int j = 0; j < 8; j++) h1[j] = s2f(w[j]);
        }
        for (int i = 0; i < CLEN; i++) {
            int l = l0 + i;
            short8 zv = *(const short8*)(zb + (size_t)l * Z_LD + zc0);
            short8 o;
#pragma unroll
            for (int j = 0; j < 8; j++) {
                float cur = s2f(zv[j]);
                float q = fsilu(wt[0][j] * h1[j] + wt[1][j] * h2[j] + wt[2][j] * h3[j] + wt[3][j] * cur);
                h1[j] = h2[j]; h2[j] = h3[j]; h3[j] = cur;
                o[j] = f2s(q);
            }
            *(short8*)(qbuf + (bL + l) * 768 + qc0) = o;
        }
    } else {
        const int k0 = (tau == 192) ? 0 : 8;
        const int nv = (tau == 192) ? 8 : 4;
        float spw[8];
#pragma unroll
        for (int j = 0; j < 8; j++) spw[j] = 0.f;
        for (int i = 0; i < CLEN; i++) {
            int l = l0 + i;
            short8 o;
#pragma unroll
            for (int j = 0; j < 8; j++) {
                float v = (j < nv) ? pwl[i][k0 + j] : 0.0f;
                short t = f2s(v);
                o[j] = t;
                spw[j] += s2f(t);
            }
            *(short8*)(csb + (size_t)l * CS_LD + 1536 + k0) = o;
        }
#pragma unroll
        for (int j = 0; j < 8; j++) srow[1536 + k0 + j] = spw[j];
    }
}

// exclusive scan of chunk sums over NCHUNK chunks, per (b, col)
__global__ void scan_mid(float* __restrict__ sums)
{
    int gid = blockIdx.x * 256 + threadIdx.x;
    if (gid >= B_SZ * 1552) return;
    int c = gid % 1552;
    int b = gid / 1552;
    float run = 0.f;
    for (int i = 0; i < NCHUNK; i++) {
        size_t idx = ((size_t)(b * NCHUNK + i)) * 1552 + c;
        float v = sums[idx];
        sums[idx] = run;
        run += v;
    }
}

// in-place cumsum over bf16 terms, 8 cols/thread, 16B loads/stores
__global__ __launch_bounds__(256) void scan_inplace(
    bf16* __restrict__ cs, const float* __restrict__ sums)
{
    const int rest = blockIdx.x;
    const int chunk = rest & (NCHUNK - 1);
    const int b = rest >> 7;
    const int tau = threadIdx.x;
    if (tau >= 194) return;
    const int c0 = tau * 8;
    float run[8];
    const float* srow = sums + (size_t)rest * 1552;
#pragma unroll
    for (int j = 0; j < 8; j++) run[j] = srow[c0 + j];
    bf16* p = cs + ((size_t)(b * L_SEQ + chunk * CLEN)) * CS_LD + c0;
    for (int i = 0; i < CLEN; i++) {
        short8 v = *(const short8*)p;
        short8 o;
#pragma unroll
        for (int j = 0; j < 8; j++) {
            run[j] += s2f(v[j]);
            o[j] = f2s(run[j]);
        }
        *(short8*)p = o;
        p += CS_LD;
    }
}

// ---------------------------------------------------------------------------
// match + gated RMSNorm, vectorized: block=192 threads, 8 cols/thread.
// Writes out_n in-place into cs cols [0,1536).
// ---------------------------------------------------------------------------
__global__ __launch_bounds__(192) void match_norm_kernel(
    bf16* __restrict__ cs, const bf16* __restrict__ qbuf,
    const bf16* __restrict__ gate, const float* __restrict__ wtab,
    const float* __restrict__ gnw)
{
    const int bl = blockIdx.x;
    bf16* csr = cs + (size_t)bl * CS_LD;
    const bf16* qr = qbuf + (size_t)bl * 768;
    const bf16* gr = gate + (size_t)bl * OUT_CPLX;
    __shared__ float inv_den[NK];
    __shared__ float wsum[3];

    if (threadIdx.x < NK)
        inv_den[threadIdx.x] = 1.0f / fmaxf(bf2f(csr[1536 + threadIdx.x]), 1e-4f);
    __syncthreads();

    const int c0 = threadIdx.x * 8;
    const int k = c0 >> 7;
    const int r0 = c0 & 127;
    const int h0 = r0 & 63;
    const bool is_im = (r0 >= 64);
    const int kq = k >> 1;
    const float idn = inv_den[k];

    short8 re8 = *(const short8*)(csr + k * 64 + h0);
    short8 im8 = *(const short8*)(csr + 768 + k * 64 + h0);
    short8 qa = *(const short8*)(qr + kq * 128 + 2 * h0);
    short8 qb = *(const short8*)(qr + kq * 128 + 2 * h0 + 8);
    short8 g8 = *(const short8*)(gr + c0);
    float4 wa = *(const float4*)(wtab + k * 64 + h0);
    float4 wb = *(const float4*)(wtab + k * 64 + h0 + 4);
    float4 na = *(const float4*)(gnw + c0);
    float4 nb = *(const float4*)(gnw + c0 + 4);
    float wreg[8] = {wa.x, wa.y, wa.z, wa.w, wb.x, wb.y, wb.z, wb.w};
    float nreg[8] = {na.x, na.y, na.z, na.w, nb.x, nb.y, nb.z, nb.w};

    float vals[8];
    float ss = 0.0f;
#pragma unroll
    for (int j = 0; j < 8; j++) {
        float sre = s2f(re8[j]) * idn;
        float sim = s2f(im8[j]) * idn;
        short qre_s = (j < 4) ? qa[2 * j] : qb[2 * (j - 4)];
        short qim_s = (j < 4) ? qa[2 * j + 1] : qb[2 * (j - 4) + 1];
        float qre = s2f(qre_s);
        float qim = s2f(qim_s);
        float m = is_im ? (sim * qre - sre * qim) : (sre * qre + sim * qim);
        m *= 0.125f * wreg[j];
        float hv = m * fsilu(s2f(g8[j]));
        vals[j] = hv;
        ss += hv * hv;
    }
    const int lane = threadIdx.x & 63;
    const int wv_id = threadIdx.x >> 6;
#pragma unroll
    for (int off = 32; off > 0; off >>= 1) ss += __shfl_down(ss, off);
    if (lane == 0) wsum[wv_id] = ss;
    __syncthreads();
    float total = wsum[0] + wsum[1] + wsum[2];
    float inv_rms = rsqrtf(total * (1.0f / (float)OUT_CPLX) + 1e-6f);
    short8 o;
#pragma unroll
    for (int j = 0; j < 8; j++) o[j] = f2s(vals[j] * inv_rms * nreg[j]);
    *(short8*)(csr + c0) = o;
}

__global__ void sentinel_kernel(float* out, float v)
{
    if (threadIdx.x == 0) out[0] = v;
}

// ---------------------------------------------------------------------------
// Workspace layout (bytes)
// ---------------------------------------------------------------------------
#define XB_OFF 0UL                 // 16384x768 bf16       25,165,824
#define WT_IN_OFF 25165824UL       // 1792x768 bf16         2,752,512 (rows 1548+ unwritten, clipped)
#define WT_GATE_OFF 27918336UL     // 1536x768 bf16         2,359,296
#define WT_OUT_OFF 30277632UL      // 768x2304 bf16         3,538,944
#define WT_RO_OFF 33816576UL       // 12x384x128 bf16       1,179,648
#define SUMS_OFF 34996224UL        // 512x1552 fp32         3,178,496
#define WTAB_OFF 38174720UL        // 768 fp32                  3,072
#define CS_OFF 38177792UL          // 16384x1552 bf16      50,855,936
#define A_OFF 89033728UL           // z0 16384x1552 bf16; later gate; later y (75,497,472)
#define QBUF_OFF 139889664UL       // 16384x768 bf16       25,165,824 (overlapped by y tail later)
#define WS_NEEDED 165055488UL      // < 166,932,480 proven available (round 2)

static inline int cdiv(long n) { return (int)((n + 255) / 256); }

extern "C" void kernel_launch(void* const* d_in, const int* in_sizes, int n_in,
                              void* d_out, int out_size, void* d_ws, size_t ws_size,
                              hipStream_t stream)
{
    const float* x = (const float*)d_in[0];
    const float* W_in = (const float*)d_in[1];
    const float* conv_w = (const float*)d_in[2];
    const float* theta_raw = (const float*)d_in[3];
    const float* w_int_raw = (const float*)d_in[4];
    const float* decay_slopes = (const float*)d_in[5];
    const float* score_scale = (const float*)d_in[6];
    const float* score_bias = (const float*)d_in[7];
    const float* phase_scale = (const float*)d_in[8];
    const float* gnw = (const float*)d_in[9];
    const float* W_readout = (const float*)d_in[10];
    const float* W_gate = (const float*)d_in[11];
    const float* W_out = (const float*)d_in[12];

    if (ws_size < WS_NEEDED) {
        sentinel_kernel<<<1, 64, 0, stream>>>((float*)d_out, (float)ws_size);
        return;
    }

    char* ws = (char*)d_ws;
    bf16* xb = (bf16*)(ws + XB_OFF);
    bf16* WT_IN = (bf16*)(ws + WT_IN_OFF);
    bf16* WT_GATE = (bf16*)(ws + WT_GATE_OFF);
    bf16* WT_OUT = (bf16*)(ws + WT_OUT_OFF);
    bf16* WT_RO = (bf16*)(ws + WT_RO_OFF);
    float* sums = (float*)(ws + SUMS_OFF);
    float* wtab = (float*)(ws + WTAB_OFF);
    bf16* cs = (bf16*)(ws + CS_OFF);
    bf16* z0 = (bf16*)(ws + A_OFF);
    bf16* gate = (bf16*)(ws + A_OFF);
    bf16* y = (bf16*)(ws + A_OFF);
    bf16* qbuf = (bf16*)(ws + QBUF_OFF);

    // 0. single prep launch: convert x, wint table, all weight transposes
    prep_kernel<<<PREP_TOTAL, 256, 0, stream>>>(
        x, w_int_raw, W_in, W_gate, W_out, W_readout,
        xb, wtab, WT_IN, WT_GATE, WT_OUT, WT_RO);

    // 1. z0 = x @ W_in (wide core, N padded to 1792, cols clipped at 1548)
    gemm_wide<<<dim3(128, 7), 256, 0, stream>>>(xb, 768, WT_IN, 768, z0, Z_LD, 768, 1548);

    // 2. terms (pw fused in-block) + chunk sums; chunk scan; in-place cumsum
    scan_terms<<<512, 256, 0, stream>>>(z0, conv_w, theta_raw, phase_scale,
                                        decay_slopes, score_scale, score_bias,
                                        cs, qbuf, sums);
    scan_mid<<<25, 256, 0, stream>>>(sums);
    scan_inplace<<<512, 256, 0, stream>>>(cs, sums);

    // 3. gate = x @ W_gate (wide core, overwrites z0)
    gemm_wide<<<dim3(128, 6), 256, 0, stream>>>(xb, 768, WT_GATE, 768, gate, 1536, 768, 1536);

    // 4. match + gated rmsnorm -> out_n in-place into cs
    match_norm_kernel<<<NROW, 192, 0, stream>>>(cs, qbuf, gate, wtab, gnw);

    // 5. readout GEMM + fused GLU -> y
    gemm_readout_glu<<<dim3(128, 3, 12), 256, 0, stream>>>(
        cs, CS_LD, 128L, WT_RO, 128, 49152L, y, 128);

    // 6. out = y @ W_out (fp32)
    gemm_kernel<false><<<dim3(128, 6), 256, 0, stream>>>(y, 2304, WT_OUT, 2304,
                                                         (float*)d_out, 768, 2304, 768);
}